// Round 9
// baseline (6208.998 us; speedup 1.0000x reference)
//
#include <hip/hip_runtime.h>
#include <math.h>

#define T_LEN 8192

typedef float f32x4 __attribute__((ext_vector_type(4)));
typedef int   i32x8 __attribute__((ext_vector_type(8)));

#define DPP_MAX(x, ctrl) fmaxf((x), __int_as_float(__builtin_amdgcn_update_dpp(0, __float_as_int(x), (ctrl), 0xF, 0xF, true)))

__device__ __forceinline__ float fsig(float x) {
    // inf-safe without clamps: exp(-x)=inf -> rcp(inf)=0; exp(-x)=0 -> 1
    float e = __expf(-x);
    return __builtin_amdgcn_rcpf(1.f + e);
}
__device__ __forceinline__ float fsig_c(float x) {
    x = fminf(30.f, fmaxf(-30.f, x));
    float e = __expf(-x);
    return __builtin_amdgcn_rcpf(1.f + e);
}
__device__ __forceinline__ float ftanh_c(float x) {
    x = fminf(15.f, fmaxf(-15.f, x));
    float e = __expf(-2.f * x);
    return (1.f - e) * __builtin_amdgcn_rcpf(1.f + e);
}

// ---- OCP e4m3fn encode (HW builtin when available, manual RTN fallback) ----
__device__ __forceinline__ unsigned char enc_e4m3(float x) {
#if __has_builtin(__builtin_amdgcn_cvt_pk_fp8_f32)
    int v = __builtin_amdgcn_cvt_pk_fp8_f32(x, 0.f, 0, false);
    return (unsigned char)(v & 0xff);
#else
    unsigned u = __float_as_uint(x);
    unsigned s = (u >> 24) & 0x80u;
    float a = fabsf(x);
    if (a > 448.f) a = 448.f;
    if (a < 9.765625e-4f) return (unsigned char)s;
    int e = ((int)((__float_as_uint(a) >> 23) & 0xffu)) - 127;
    int eu = e < -6 ? -6 : e;
    float ulp = exp2f((float)(eu - 3));
    float q = rintf(a / ulp);
    int mant, ee;
    if (eu == -6 && q < 8.f) { mant = (int)q; ee = 0; }
    else {
        if (q >= 16.f) { q *= 0.5f; eu += 1; }
        mant = (int)q - 8; ee = eu + 7;
        if (ee > 15 || (ee == 15 && mant > 6)) { ee = 15; mant = 6; }
    }
    return (unsigned char)(s | (unsigned)(ee << 3) | (unsigned)mant);
#endif
}
__device__ __forceinline__ unsigned pk4(float a, float b, float c, float d) {
    return (unsigned)enc_e4m3(a) | ((unsigned)enc_e4m3(b) << 8)
         | ((unsigned)enc_e4m3(c) << 16) | ((unsigned)enc_e4m3(d) << 24);
}

// ---- OCP e2m3 (fp6) encode: sign(1) exp(2,bias1) man(3); max 7.5 ----
__device__ __forceinline__ unsigned enc_e2m3(float x) {
    unsigned s = (__float_as_uint(x) >> 31) << 5;
    float a = fabsf(x);
    a = fminf(a, 7.5f);
    if (a < 0.0625f) return s;
    int e = ((int)((__float_as_uint(a) >> 23) & 0xffu)) - 127;
    int eu = e < 0 ? 0 : e;
    float ulp = __int_as_float((unsigned)(eu + 124) << 23);     // 2^(eu-3)
    float q = rintf(a * __builtin_amdgcn_rcpf(ulp));
    int E, M;
    if (e < 0) {
        if (q >= 8.f) { E = 1; M = 0; }
        else { E = 0; M = (int)q; }
    } else {
        if (q >= 16.f) { q = 8.f; eu += 1; }
        if (eu > 2) { E = 3; M = 7; }
        else { E = eu + 1; M = (int)q - 8; }
    }
    return s | (unsigned)(E << 3) | (unsigned)M;
}

// ---------------------------------------------------------------------------
// Kernel 0: one-shot pre-pass — quantize W_hh to packed fp6 (e2m3, x32).
// Tuple index = (gt*2 + kt)*64 + l, gt = global 16-row tile 0..63.
// ---------------------------------------------------------------------------
__global__ __launch_bounds__(256) void pack_w6(
    const float* __restrict__ w_hh,   // (1024, 256)
    unsigned* __restrict__ w6)        // 8192 items x 8 dwords
{
    int idx = blockIdx.x * 256 + threadIdx.x;   // 0..8191
    int l  = idx & 63;
    int kt = (idx >> 6) & 1;
    int gt = idx >> 7;                            // 0..63
    int rw = l & 15, kg = l >> 4;
    int rowp = (gt << 4) + rw;                    // permuted row 4u+gate
    int orow = ((rowp & 3) << 8) + (rowp >> 2);   // original gate-major row
    const float* s = w_hh + (size_t)orow * 256 + 128 * kt + 32 * kg;
    unsigned d[6] = {0, 0, 0, 0, 0, 0};
#pragma unroll
    for (int j = 0; j < 32; ++j) {
        unsigned c = enc_e2m3(s[j] * 32.f);
        int bit = 6 * j;
        d[bit >> 5] |= c << (bit & 31);
        if ((bit & 31) > 26) d[(bit >> 5) + 1] |= c >> (32 - (bit & 31));
    }
    unsigned* o = w6 + (size_t)idx * 8;
    o[0] = d[0]; o[1] = d[1]; o[2] = d[2];
    o[3] = d[3]; o[4] = d[4]; o[5] = d[5];
    o[6] = 0;    o[7] = 0;
}

// ---------------------------------------------------------------------------
// Kernel 1: pre = relu(embed_W[docs]) @ w_ih^T + (b_ih + b_hh)   (T x 1024)
// Output columns PERMUTED: col' = 4*unit + gate
// ---------------------------------------------------------------------------
__global__ __launch_bounds__(256, 4) void gemm_pre(
    const int* __restrict__ docs,
    const float* __restrict__ embW,
    const float* __restrict__ w_ih,
    const float* __restrict__ b_ih,
    const float* __restrict__ b_hh,
    float* __restrict__ pre)
{
    __shared__ __align__(16) float As[16][68];
    __shared__ __align__(16) float Bs[16][68];
    __shared__ int rowid[64];
    const int bt = blockIdx.x;
    const int bj = blockIdx.y;
    const int tid = threadIdx.x;
    if (tid < 64) rowid[tid] = docs[bt * 64 + tid];
    __syncthreads();
    const int ti = tid & 15, tj = tid >> 4;
    const int r = tid & 63;
    const int kk4 = (tid >> 6) * 4;
    float acc[4][4];
#pragma unroll
    for (int ii = 0; ii < 4; ++ii)
#pragma unroll
        for (int jj = 0; jj < 4; ++jj) acc[ii][jj] = 0.f;

    for (int k0 = 0; k0 < 256; k0 += 16) {
        float4 av = *(const float4*)(embW + (size_t)rowid[r] * 256 + k0 + kk4);
        float4 bv = *(const float4*)(w_ih + (size_t)(bj * 64 + r) * 256 + k0 + kk4);
        As[kk4 + 0][r] = fmaxf(av.x, 0.f);
        As[kk4 + 1][r] = fmaxf(av.y, 0.f);
        As[kk4 + 2][r] = fmaxf(av.z, 0.f);
        As[kk4 + 3][r] = fmaxf(av.w, 0.f);
        Bs[kk4 + 0][r] = bv.x;
        Bs[kk4 + 1][r] = bv.y;
        Bs[kk4 + 2][r] = bv.z;
        Bs[kk4 + 3][r] = bv.w;
        __syncthreads();
#pragma unroll
        for (int kk = 0; kk < 16; ++kk) {
            float4 a = *(const float4*)&As[kk][ti * 4];
            float4 b = *(const float4*)&Bs[kk][tj * 4];
            acc[0][0] += a.x * b.x; acc[0][1] += a.x * b.y; acc[0][2] += a.x * b.z; acc[0][3] += a.x * b.w;
            acc[1][0] += a.y * b.x; acc[1][1] += a.y * b.y; acc[1][2] += a.y * b.z; acc[1][3] += a.y * b.w;
            acc[2][0] += a.z * b.x; acc[2][1] += a.z * b.y; acc[2][2] += a.z * b.z; acc[2][3] += a.z * b.w;
            acc[3][0] += a.w * b.x; acc[3][1] += a.w * b.y; acc[3][2] += a.w * b.z; acc[3][3] += a.w * b.w;
        }
        __syncthreads();
    }
#pragma unroll
    for (int ii = 0; ii < 4; ++ii) {
        int t = bt * 64 + ti * 4 + ii;
#pragma unroll
        for (int jj = 0; jj < 4; ++jj) {
            int j = bj * 64 + tj * 4 + jj;
            int jp = ((j & 255) << 2) | (j >> 8);
            pre[(size_t)t * 1024 + jp] = acc[ii][jj] + b_ih[j] + b_hh[j];
        }
    }
}

// ---------------------------------------------------------------------------
// Kernel 2a (primary): 4-wave MX-fp6 scan. 256 threads, 1 wave/SIMD,
// __launch_bounds__(256,1) -> up to 512 unified regs/wave (wA in AGPRs).
// Every lane owns one unit: lane l of wave w -> tile rt=l&15, kg=l>>4,
// unit u=64w+4rt+kg; acc[rt] regs 0..3 = the 4 gates of u (cols identical).
// No exec-masked waste, no acc zero-init (literal-zero C on kt=0 MFMA),
// no ldsPre (direct per-lane f32x4 prefetch of pre[t+1]).
// ---------------------------------------------------------------------------
__global__ __launch_bounds__(256, 1) void lstm_scan_mx6w4(
    const float* __restrict__ pre,    // (T, 1024), permuted cols 4u+gate
    const unsigned* __restrict__ w6,  // packed fp6 weights
    float* __restrict__ hs)           // (T, 256) fp32
{
    const int tid = threadIdx.x;
    const int w  = tid >> 6;          // wave 0..3
    const int l  = tid & 63;
    const int rto = l & 15;           // owned tile
    const int kg  = l >> 4;           // k-group / unit sub-index
    const float INV = 1.f / 128.f;    // 1/(32*4)

    __shared__ __align__(16) unsigned char h6pk[2][256];  // 8 windows x 32B

    // ---- weights: 16 tiles x 2 kt (compiler places in AGPRs) ----
    i32x8 wA[16][2];
#pragma unroll
    for (int rtt = 0; rtt < 16; ++rtt) {
#pragma unroll
        for (int kt = 0; kt < 2; ++kt) {
            int gt = 16 * w + rtt;
            const unsigned* s = w6 + (size_t)((gt * 2 + kt) * 64 + l) * 8;
            uint4 lo = *(const uint4*)s;
            uint2 hi = *(const uint2*)(s + 4);
            i32x8 v;
            v[0] = (int)lo.x; v[1] = (int)lo.y; v[2] = (int)lo.z;
            v[3] = (int)lo.w; v[4] = (int)hi.x; v[5] = (int)hi.y;
            v[6] = 0; v[7] = 0;
            wA[rtt][kt] = v;
        }
    }

    for (int i = tid; i < 512; i += 256) ((unsigned char*)h6pk)[i] = 0;

    const int u = 64 * w + 4 * rto + kg;                  // owned unit
    float c_st = 0.f;

    // writer-lane constants: wave w packs windows m=2w,2w+1 (48 bytes)
    const bool iswr = (l < 48);
    const int s_  = (l >= 24) ? 1 : 0;
    const int b_  = l - 24 * s_;
    const int j0  = (4 * b_) / 3;
    const int rsh = 8 * b_ - 6 * j0;                      // 0,2,4
    const int j1  = j0 + 1;
    const int lj0 = 16 * (j0 & 3) + 8 * s_ + (j0 >> 2);
    const int lj1 = 16 * (j1 & 3) + 8 * s_ + (j1 >> 2);
    const int wofs = (2 * w + s_) * 32 + b_;

    f32x4 p4c = *(const f32x4*)(pre + 4 * u);             // t = 0
    const float* pp = pre + 1024 + 4 * u;
    float* hsp = hs + u;
    __syncthreads();

    for (int t = 0; t < T_LEN; ++t) {
        const int PW = t & 1;
        const int PR = PW ^ 1;

        // prefetch next step's gate bias (global, L2-resident)
        f32x4 p4n = *(const f32x4*)pp;
        if (t + 2 < T_LEN) pp += 1024;

        // B: packed fp6 windows (kt,kg), 24B direct reads
        i32x8 bq0, bq1;
        {
            const unsigned char* bp0 = &h6pk[PR][kg * 32];
            uint4 lo = *(const uint4*)bp0;
            uint2 hi = *(const uint2*)(bp0 + 16);
            bq0[0] = (int)lo.x; bq0[1] = (int)lo.y; bq0[2] = (int)lo.z;
            bq0[3] = (int)lo.w; bq0[4] = (int)hi.x; bq0[5] = (int)hi.y;
            bq0[6] = 0; bq0[7] = 0;
            const unsigned char* bp1 = &h6pk[PR][(4 + kg) * 32];
            uint4 lo1 = *(const uint4*)bp1;
            uint2 hi1 = *(const uint2*)(bp1 + 16);
            bq1[0] = (int)lo1.x; bq1[1] = (int)lo1.y; bq1[2] = (int)lo1.z;
            bq1[3] = (int)lo1.w; bq1[4] = (int)hi1.x; bq1[5] = (int)hi1.y;
            bq1[6] = 0; bq1[7] = 0;
        }

        // MFMA GEMV: 16 tiles x 2 kt; kt=0 takes literal-zero C (no acc init)
        f32x4 acc[16];
#pragma unroll
        for (int rtt = 0; rtt < 16; ++rtt) {
            acc[rtt] = __builtin_amdgcn_mfma_scale_f32_16x16x128_f8f6f4(
                wA[rtt][0], bq0, (f32x4){0.f, 0.f, 0.f, 0.f},
                2, 2, 0, 0x7f7f7f7f, 0, 0x7f7f7f7f);
            acc[rtt] = __builtin_amdgcn_mfma_scale_f32_16x16x128_f8f6f4(
                wA[rtt][1], bq1, acc[rtt],
                2, 2, 0, 0x7f7f7f7f, 0, 0x7f7f7f7f);
        }

        // select owned tile (static 15-deep ladder), all 64 lanes active
        f32x4 av = acc[0];
#pragma unroll
        for (int k = 1; k < 16; ++k) av = (rto == k) ? acc[k] : av;

        float gi = fmaf(av.x, INV, p4c.x);
        float gf = fmaf(av.y, INV, p4c.y);
        float gg = fmaf(av.z, INV, p4c.z);
        float go = fmaf(av.w, INV, p4c.w);
        float si = fsig(gi);
        float sf = fsig(gf);
        float tg = 2.f * fsig(2.f * gg) - 1.f;    // tanh, clamp-free
        float so = fsig(go);
        c_st = sf * c_st + si * tg;
        float h = so * (2.f * fsig(2.f * c_st) - 1.f);
        hsp[0] = h;
        hsp += 256;
        int code = (int)enc_e2m3(h * 4.f);

        // cooperative 6-bit pack: byte b_ of window 2w+s_ from codes j0,j1
        int c0 = __shfl(code, lj0, 64);
        int c1 = __shfl(code, lj1, 64);
        if (iswr) {
            unsigned byte = (((unsigned)c0 >> rsh) | ((unsigned)c1 << (6 - rsh))) & 0xffu;
            h6pk[PW][wofs] = (unsigned char)byte;
        }

        p4c = p4n;
        __syncthreads();
    }
}

// ---------------------------------------------------------------------------
// Kernel 2b (fallback 1): round-8 proven 8-wave MX-fp6 scan (unchanged).
// ---------------------------------------------------------------------------
__global__ __launch_bounds__(512, 2) void lstm_scan_mx6(
    const float* __restrict__ pre,
    const unsigned* __restrict__ w6,
    float* __restrict__ hs)
{
    const int tid = threadIdx.x;
    const int w  = tid >> 6;
    const int l  = tid & 63;
    const int rw = l & 15;
    const int kg = l >> 4;
    const float INV = 1.f / 128.f;

    __shared__ __align__(16) unsigned char h6pk[2][256];
    __shared__ __align__(16) float ldsPre[2][1024];

    i32x8 wA[8][2];
#pragma unroll
    for (int rt = 0; rt < 8; ++rt) {
#pragma unroll
        for (int kt = 0; kt < 2; ++kt) {
            const unsigned* s = w6 + (size_t)(((w * 8 + rt) * 2 + kt) * 64 + l) * 8;
            uint4 lo = *(const uint4*)s;
            uint2 hi = *(const uint2*)(s + 4);
            i32x8 v;
            v[0] = (int)lo.x; v[1] = (int)lo.y; v[2] = (int)lo.z;
            v[3] = (int)lo.w; v[4] = (int)hi.x; v[5] = (int)hi.y;
            v[6] = 0; v[7] = 0;
            wA[rt][kt] = v;
        }
    }

    for (int i = tid; i < 512; i += 512) h6pk[0][i] = 0;
    {
        float2 p = *(const float2*)(pre + 2 * tid);
        *(float2*)&ldsPre[0][2 * tid] = p;
    }

    const bool isup = (rw < 8);
    const int u = 32 * w + 4 * (rw & 7) + kg;
    float c_st = 0.f;

    const bool iswr = (rw < 8) && (kg < 3);
    const int bby = 8 * kg + rw;
    const int j0  = (4 * bby) / 3;
    const int rsh = 8 * bby - 6 * j0;
    const int lj0 = 16 * (j0 & 3) + (j0 >> 2);
    const int j1  = j0 + 1;
    const int lj1 = 16 * (j1 & 3) + (j1 >> 2);

    const float* pnext = pre + 1024 + 2 * tid;
    float* hsp = hs + u;
    __syncthreads();

    for (int t = 0; t < T_LEN; ++t) {
        const int PW = t & 1;
        const int PR = PW ^ 1;

        f32x4 p4 = *(const f32x4*)&ldsPre[PW][4 * u];

        float2 pv = *(const float2*)pnext;
        if (t + 2 < T_LEN) pnext += 1024;

        i32x8 bq[2];
#pragma unroll
        for (int kt = 0; kt < 2; ++kt) {
            const unsigned char* bp = &h6pk[PR][(4 * kt + kg) * 32];
            uint4 lo = *(const uint4*)bp;
            uint2 hi = *(const uint2*)(bp + 16);
            i32x8 b;
            b[0] = (int)lo.x; b[1] = (int)lo.y; b[2] = (int)lo.z; b[3] = (int)lo.w;
            b[4] = (int)hi.x; b[5] = (int)hi.y; b[6] = 0; b[7] = 0;
            bq[kt] = b;
        }

        f32x4 acc[8];
#pragma unroll
        for (int rt = 0; rt < 8; ++rt) acc[rt] = (f32x4){0.f, 0.f, 0.f, 0.f};
#pragma unroll
        for (int rt = 0; rt < 8; ++rt)
#pragma unroll
            for (int kt = 0; kt < 2; ++kt)
                acc[rt] = __builtin_amdgcn_mfma_scale_f32_16x16x128_f8f6f4(
                    wA[rt][kt], bq[kt], acc[rt],
                    2, 2, 0, 0x7f7f7f7f, 0, 0x7f7f7f7f);

        int code = 0;
        if (isup) {
            f32x4 av = acc[0];
            av = (rw == 1) ? acc[1] : av;
            av = (rw == 2) ? acc[2] : av;
            av = (rw == 3) ? acc[3] : av;
            av = (rw == 4) ? acc[4] : av;
            av = (rw == 5) ? acc[5] : av;
            av = (rw == 6) ? acc[6] : av;
            av = (rw == 7) ? acc[7] : av;
            float gi = fmaf(av.x, INV, p4.x);
            float gf = fmaf(av.y, INV, p4.y);
            float gg = fmaf(av.z, INV, p4.z);
            float go = fmaf(av.w, INV, p4.w);
            float si = fsig_c(gi);
            float sf = fsig_c(gf);
            float tg = ftanh_c(gg);
            float so = fsig_c(go);
            c_st = sf * c_st + si * tg;
            float h = so * ftanh_c(c_st);
            hsp[0] = h;
            code = (int)enc_e2m3(h * 4.f);
        }
        hsp += 256;

        int c0 = __shfl(code, lj0, 64);
        int c1 = __shfl(code, lj1, 64);
        if (iswr) {
            unsigned byte = (((unsigned)c0 >> rsh) | ((unsigned)c1 << (6 - rsh))) & 0xffu;
            h6pk[PW][w * 32 + bby] = (unsigned char)byte;
        }

        *(float2*)&ldsPre[PR][2 * tid] = pv;

        __syncthreads();
    }
}

// ---------------------------------------------------------------------------
// Kernel 2c (fallback 2): round-6 proven MX-fp8 scan.
// ---------------------------------------------------------------------------
__global__ __launch_bounds__(512, 2) void lstm_scan_mx8(
    const float* __restrict__ pre,
    const float* __restrict__ w_hh,
    float* __restrict__ hs)
{
    const int tid = threadIdx.x;
    const int w  = tid >> 6;
    const int l  = tid & 63;
    const int rw = l & 15;
    const int kg = l >> 4;
    const float INV = 1.f / 32768.f;

    __shared__ __align__(16) unsigned char h8[2 * 256];
    __shared__ __align__(16) float ldsPre[2][1024];

    i32x8 wA[8][2];
#pragma unroll
    for (int rt = 0; rt < 8; ++rt) {
#pragma unroll
        for (int kt = 0; kt < 2; ++kt) {
            int rowp = ((8 * w + rt) << 4) + rw;
            int orow = ((rowp & 3) << 8) + (rowp >> 2);
            const float* s = w_hh + (size_t)orow * 256 + 128 * kt + 32 * kg;
            i32x8 v;
#pragma unroll
            for (int d = 0; d < 8; ++d) {
                float4 f = *(const float4*)(s + 4 * d);
                v[d] = (int)pk4(f.x * 512.f, f.y * 512.f, f.z * 512.f, f.w * 512.f);
            }
            wA[rt][kt] = v;
        }
    }

    for (int i = tid; i < 512; i += 512) h8[i] = 0;
    {
        float2 p = *(const float2*)(pre + 2 * tid);
        *(float2*)&ldsPre[0][2 * tid] = p;
    }
    float c_st = 0.f;
    const bool isup = (rw < 8);
    const int u = 32 * w + 4 * (rw & 7) + kg;
    const float* pnext = pre + 1024 + 2 * tid;
    float* hsp = hs + u;
    __syncthreads();

    for (int t = 0; t < T_LEN; ++t) {
        const int PW = t & 1;
        const int PR = PW ^ 1;

        f32x4 p4 = *(const f32x4*)&ldsPre[PW][4 * u];

        float2 pv = *(const float2*)pnext;
        if (t + 2 < T_LEN) pnext += 1024;

        i32x8 bq[2];
#pragma unroll
        for (int kt = 0; kt < 2; ++kt) {
            const unsigned char* bp = &h8[PR * 256 + 128 * kt + 32 * kg];
            uint4 lo = *(const uint4*)bp;
            uint4 hi = *(const uint4*)(bp + 16);
            i32x8 b;
            b[0] = (int)lo.x; b[1] = (int)lo.y; b[2] = (int)lo.z; b[3] = (int)lo.w;
            b[4] = (int)hi.x; b[5] = (int)hi.y; b[6] = (int)hi.z; b[7] = (int)hi.w;
            bq[kt] = b;
        }

        f32x4 acc[8];
#pragma unroll
        for (int rt = 0; rt < 8; ++rt) acc[rt] = (f32x4){0.f, 0.f, 0.f, 0.f};
#pragma unroll
        for (int rt = 0; rt < 8; ++rt)
#pragma unroll
            for (int kt = 0; kt < 2; ++kt)
                acc[rt] = __builtin_amdgcn_mfma_scale_f32_16x16x128_f8f6f4(
                    wA[rt][kt], bq[kt], acc[rt],
                    0, 0, 0, 0x7f7f7f7f, 0, 0x7f7f7f7f);

        if (isup) {
            f32x4 av = acc[0];
            av = (rw == 1) ? acc[1] : av;
            av = (rw == 2) ? acc[2] : av;
            av = (rw == 3) ? acc[3] : av;
            av = (rw == 4) ? acc[4] : av;
            av = (rw == 5) ? acc[5] : av;
            av = (rw == 6) ? acc[6] : av;
            av = (rw == 7) ? acc[7] : av;
            float gi = fmaf(av.x, INV, p4.x);
            float gf = fmaf(av.y, INV, p4.y);
            float gg = fmaf(av.z, INV, p4.z);
            float go = fmaf(av.w, INV, p4.w);
            float si = fsig_c(gi);
            float sf = fsig_c(gf);
            float tg = ftanh_c(gg);
            float so = fsig_c(go);
            c_st = sf * c_st + si * tg;
            float h = so * ftanh_c(c_st);
            hsp[0] = h;
            h8[PW * 256 + u] = enc_e4m3(h * 64.f);
        }
        hsp += 256;

        *(float2*)&ldsPre[PR][2 * tid] = pv;

        __syncthreads();
    }
}

// ---------------------------------------------------------------------------
// Kernel 3: conv (FN=128, FL=5) over hs + per-block max over its 64 t's.
// ---------------------------------------------------------------------------
__global__ __launch_bounds__(256) void conv_pool(
    const float* __restrict__ hs,
    const float* __restrict__ cw,
    const float* __restrict__ cb,
    float* __restrict__ part)
{
    __shared__ __align__(16) float hst[68 * 260];
    __shared__ __align__(16) float cwS[128 * 68];
    const int blk = blockIdx.x;
    const int t0 = blk * 64;
    const int tid = threadIdx.x;
    const int i = tid & 15;
    const int g = tid >> 4;

    for (int e = tid; e < 68 * 64; e += 256) {
        int rr = e >> 6;
        int c4 = (e & 63) * 4;
        int tg = t0 + rr; if (tg > 8191) tg = 8191;
        float4 v = *(const float4*)(hs + (size_t)tg * 256 + c4);
        *(float4*)&hst[rr * 260 + c4] = v;
    }

    float acc[4][8];
#pragma unroll
    for (int tt = 0; tt < 4; ++tt)
#pragma unroll
        for (int j = 0; j < 8; ++j) acc[tt][j] = 0.f;

    for (int l = 0; l < 5; ++l) {
        for (int hc = 0; hc < 4; ++hc) {
            __syncthreads();
            {
                int n = tid >> 1;
                int hb = (tid & 1) * 32;
                const float* src = cw + (size_t)n * 1280 + l * 256 + hc * 64 + hb;
                float* dst = &cwS[n * 68 + hb];
#pragma unroll
                for (int q = 0; q < 8; ++q) {
                    float4 v = *(const float4*)(src + 4 * q);
                    *(float4*)(dst + 4 * q) = v;
                }
            }
            __syncthreads();
#pragma unroll 4
            for (int q = 0; q < 16; ++q) {
                float4 hvv[4];
#pragma unroll
                for (int tt = 0; tt < 4; ++tt)
                    hvv[tt] = *(const float4*)&hst[(i + 16 * tt + l) * 260 + hc * 64 + 4 * q];
#pragma unroll
                for (int j = 0; j < 8; ++j) {
                    float4 wv = *(const float4*)&cwS[(g + 16 * j) * 68 + 4 * q];
#pragma unroll
                    for (int tt = 0; tt < 4; ++tt) {
                        acc[tt][j] += hvv[tt].x * wv.x + hvv[tt].y * wv.y
                                    + hvv[tt].z * wv.z + hvv[tt].w * wv.w;
                    }
                }
            }
        }
    }

    float m[8];
#pragma unroll
    for (int j = 0; j < 8; ++j) {
        int n = g + 16 * j;
        float cbn = cb[n];
        float mm = -INFINITY;
#pragma unroll
        for (int tt = 0; tt < 4; ++tt) {
            int t = t0 + i + 16 * tt;
            float v = acc[tt][j] + cbn;
            if (t < 8188) mm = fmaxf(mm, v);
        }
        mm = DPP_MAX(mm, 0xB1);
        mm = DPP_MAX(mm, 0x4E);
        mm = DPP_MAX(mm, 0x141);
        mm = DPP_MAX(mm, 0x140);
        m[j] = mm;
    }
    if (i == 0) {
#pragma unroll
        for (int j = 0; j < 8; ++j)
            part[(size_t)blk * 128 + g + 16 * j] = m[j];
    }
}

// ---------------------------------------------------------------------------
// Kernel 4: final head — pool-reduce, logits, log_softmax, loss + acc.
// ---------------------------------------------------------------------------
__global__ void final_head(
    const float* __restrict__ part,
    const float* __restrict__ logits_w,
    const float* __restrict__ logits_b,
    const int* __restrict__ labels,
    float* __restrict__ out)
{
    __shared__ float pooled[128];
    __shared__ float lgt[20];
    int tid = threadIdx.x;
    float mx = -INFINITY;
    for (int b = 0; b < 128; ++b) mx = fmaxf(mx, part[(size_t)b * 128 + tid]);
    pooled[tid] = mx;
    __syncthreads();
    if (tid < 20) {
        float s = logits_b[tid];
        for (int k = 0; k < 128; ++k) s += logits_w[tid * 128 + k] * pooled[k];
        lgt[tid] = s;
    }
    __syncthreads();
    if (tid == 0) {
        float m = lgt[0]; int am = 0;
        for (int c2 = 1; c2 < 20; ++c2) { if (lgt[c2] > m) { m = lgt[c2]; am = c2; } }
        float se = 0.f;
        for (int c2 = 0; c2 < 20; ++c2) se += expf(lgt[c2] - m);
        float lse = m + logf(se);
        int lbl = labels[0];
        out[0] = -(lgt[lbl] - lse);
        out[1] = (am == lbl) ? 1.f : 0.f;
    }
}

// ---------------------------------------------------------------------------
extern "C" void kernel_launch(void* const* d_in, const int* in_sizes, int n_in,
                              void* d_out, int out_size, void* d_ws, size_t ws_size,
                              hipStream_t stream) {
    (void)in_sizes; (void)n_in; (void)out_size;
    const int*   docs   = (const int*)d_in[0];
    const int*   labels = (const int*)d_in[2];
    const float* embW   = (const float*)d_in[4];
    const float* w_ih   = (const float*)d_in[5];
    const float* w_hh   = (const float*)d_in[6];
    const float* b_ih   = (const float*)d_in[7];
    const float* b_hh   = (const float*)d_in[8];
    const float* cw     = (const float*)d_in[9];
    const float* cb     = (const float*)d_in[10];
    const float* lw     = (const float*)d_in[11];
    const float* lb     = (const float*)d_in[12];
    float* out = (float*)d_out;

    char* ws = (char*)d_ws;
    float*    pre  = (float*)(ws);                 // 33554432 B
    float*    hs   = (float*)(ws + 33554432);      //  8388608 B
    float*    part = (float*)(ws + 41943040);      //    65536 B
    unsigned* w6   = (unsigned*)(ws + 42008576);   //   262144 B

    bool ws_ok = (ws_size >= (size_t)42270720);
    hipFuncAttributes a4, a6;
    bool ok4 = ws_ok
        && (hipFuncGetAttributes(&a4, (const void*)lstm_scan_mx6w4) == hipSuccess)
        && (a4.localSizeBytes == 0);
    bool ok6 = ws_ok
        && (hipFuncGetAttributes(&a6, (const void*)lstm_scan_mx6) == hipSuccess)
        && (a6.localSizeBytes == 0);

    gemm_pre<<<dim3(128, 16, 1), 256, 0, stream>>>(docs, embW, w_ih, b_ih, b_hh, pre);
    if (ok4 || ok6) {
        pack_w6<<<32, 256, 0, stream>>>(w_hh, w6);
        if (ok4) lstm_scan_mx6w4<<<1, 256, 0, stream>>>(pre, w6, hs);
        else     lstm_scan_mx6<<<1, 512, 0, stream>>>(pre, w6, hs);
    } else {
        lstm_scan_mx8<<<1, 512, 0, stream>>>(pre, w_hh, hs);
    }
    conv_pool<<<128, 256, 0, stream>>>(hs, cw, cb, part);
    final_head<<<1, 128, 0, stream>>>(part, lw, lb, labels, out);
}

// Round 10
// 5956.092 us; speedup vs baseline: 1.0425x; 1.0425x over previous
//
#include <hip/hip_runtime.h>
#include <math.h>

#define T_LEN 8192

typedef float f32x4 __attribute__((ext_vector_type(4)));
typedef int   i32x8 __attribute__((ext_vector_type(8)));

#define DPP_MAX(x, ctrl) fmaxf((x), __int_as_float(__builtin_amdgcn_update_dpp(0, __float_as_int(x), (ctrl), 0xF, 0xF, true)))

// LDS-only barrier: drain LDS ops, but leave global loads/stores in flight
// (classic __syncthreads drains vmcnt(0) too, pulling the pre-prefetch's
// ~200-500cy L2 latency into every step).
#define BAR_LDS() do { \
    __builtin_amdgcn_sched_barrier(0); \
    asm volatile("s_waitcnt lgkmcnt(0)" ::: "memory"); \
    __builtin_amdgcn_s_barrier(); \
    __builtin_amdgcn_sched_barrier(0); \
} while (0)

__device__ __forceinline__ float fsig(float x) {
    float e = __expf(-x);
    return __builtin_amdgcn_rcpf(1.f + e);
}
__device__ __forceinline__ float fsig_c(float x) {
    x = fminf(30.f, fmaxf(-30.f, x));
    float e = __expf(-x);
    return __builtin_amdgcn_rcpf(1.f + e);
}
__device__ __forceinline__ float ftanh_c(float x) {
    x = fminf(15.f, fmaxf(-15.f, x));
    float e = __expf(-2.f * x);
    return (1.f - e) * __builtin_amdgcn_rcpf(1.f + e);
}

// ---- OCP e4m3fn encode ----
__device__ __forceinline__ unsigned char enc_e4m3(float x) {
#if __has_builtin(__builtin_amdgcn_cvt_pk_fp8_f32)
    int v = __builtin_amdgcn_cvt_pk_fp8_f32(x, 0.f, 0, false);
    return (unsigned char)(v & 0xff);
#else
    unsigned u = __float_as_uint(x);
    unsigned s = (u >> 24) & 0x80u;
    float a = fabsf(x);
    if (a > 448.f) a = 448.f;
    if (a < 9.765625e-4f) return (unsigned char)s;
    int e = ((int)((__float_as_uint(a) >> 23) & 0xffu)) - 127;
    int eu = e < -6 ? -6 : e;
    float ulp = exp2f((float)(eu - 3));
    float q = rintf(a / ulp);
    int mant, ee;
    if (eu == -6 && q < 8.f) { mant = (int)q; ee = 0; }
    else {
        if (q >= 16.f) { q *= 0.5f; eu += 1; }
        mant = (int)q - 8; ee = eu + 7;
        if (ee > 15 || (ee == 15 && mant > 6)) { ee = 15; mant = 6; }
    }
    return (unsigned char)(s | (unsigned)(ee << 3) | (unsigned)mant);
#endif
}
__device__ __forceinline__ unsigned pk4(float a, float b, float c, float d) {
    return (unsigned)enc_e4m3(a) | ((unsigned)enc_e4m3(b) << 8)
         | ((unsigned)enc_e4m3(c) << 16) | ((unsigned)enc_e4m3(d) << 24);
}

// ---- OCP e2m3 (fp6) encode: full version (pre-pass only) ----
__device__ __forceinline__ unsigned enc_e2m3(float x) {
    unsigned s = (__float_as_uint(x) >> 31) << 5;
    float a = fabsf(x);
    a = fminf(a, 7.5f);
    if (a < 0.0625f) return s;
    int e = ((int)((__float_as_uint(a) >> 23) & 0xffu)) - 127;
    int eu = e < 0 ? 0 : e;
    float ulp = __int_as_float((unsigned)(eu + 124) << 23);     // 2^(eu-3)
    float q = rintf(a * __builtin_amdgcn_rcpf(ulp));
    int E, M;
    if (e < 0) {
        if (q >= 8.f) { E = 1; M = 0; }
        else { E = 0; M = (int)q; }
    } else {
        if (q >= 16.f) { q = 8.f; eu += 1; }
        if (eu > 2) { E = 3; M = 7; }
        else { E = eu + 1; M = (int)q - 8; }
    }
    return s | (unsigned)(E << 3) | (unsigned)M;
}

// ---- fast e2m3 for a = 4|h| < 4: piecewise-linear code, bit-identical ----
__device__ __forceinline__ int enc_e2m3_h4(float h) {
    float x = h * 4.f;
    float a = fabsf(x);
    int c1 = (int)rintf(a * 8.f);        // a < 2 : denorm + E1 linear region
    int c2 = (int)rintf(a * 4.f) + 8;    // 2 <= a < 4 : E2 region (q=16 -> 24)
    int mag = (a < 2.f) ? c1 : c2;
    return mag | (int)((__float_as_uint(h) >> 26) & 32u);
}

// ---------------------------------------------------------------------------
// Kernel 0: one-shot pre-pass — quantize W_hh to packed fp6 (e2m3, x32).
// ---------------------------------------------------------------------------
__global__ __launch_bounds__(256) void pack_w6(
    const float* __restrict__ w_hh,   // (1024, 256)
    unsigned* __restrict__ w6)        // 8192 items x 8 dwords
{
    int idx = blockIdx.x * 256 + threadIdx.x;   // 0..8191
    int l  = idx & 63;
    int kt = (idx >> 6) & 1;
    int gt = idx >> 7;                            // 0..63
    int rw = l & 15, kg = l >> 4;
    int rowp = (gt << 4) + rw;                    // permuted row 4u+gate
    int orow = ((rowp & 3) << 8) + (rowp >> 2);   // original gate-major row
    const float* s = w_hh + (size_t)orow * 256 + 128 * kt + 32 * kg;
    unsigned d[6] = {0, 0, 0, 0, 0, 0};
#pragma unroll
    for (int j = 0; j < 32; ++j) {
        unsigned c = enc_e2m3(s[j] * 32.f);
        int bit = 6 * j;
        d[bit >> 5] |= c << (bit & 31);
        if ((bit & 31) > 26) d[(bit >> 5) + 1] |= c >> (32 - (bit & 31));
    }
    unsigned* o = w6 + (size_t)idx * 8;
    o[0] = d[0]; o[1] = d[1]; o[2] = d[2];
    o[3] = d[3]; o[4] = d[4]; o[5] = d[5];
    o[6] = 0;    o[7] = 0;
}

// ---------------------------------------------------------------------------
// Kernel 1: pre = relu(embed_W[docs]) @ w_ih^T + (b_ih + b_hh)   (T x 1024)
// Output columns PERMUTED: col' = 4*unit + gate
// ---------------------------------------------------------------------------
__global__ __launch_bounds__(256, 4) void gemm_pre(
    const int* __restrict__ docs,
    const float* __restrict__ embW,
    const float* __restrict__ w_ih,
    const float* __restrict__ b_ih,
    const float* __restrict__ b_hh,
    float* __restrict__ pre)
{
    __shared__ __align__(16) float As[16][68];
    __shared__ __align__(16) float Bs[16][68];
    __shared__ int rowid[64];
    const int bt = blockIdx.x;
    const int bj = blockIdx.y;
    const int tid = threadIdx.x;
    if (tid < 64) rowid[tid] = docs[bt * 64 + tid];
    __syncthreads();
    const int ti = tid & 15, tj = tid >> 4;
    const int r = tid & 63;
    const int kk4 = (tid >> 6) * 4;
    float acc[4][4];
#pragma unroll
    for (int ii = 0; ii < 4; ++ii)
#pragma unroll
        for (int jj = 0; jj < 4; ++jj) acc[ii][jj] = 0.f;

    for (int k0 = 0; k0 < 256; k0 += 16) {
        float4 av = *(const float4*)(embW + (size_t)rowid[r] * 256 + k0 + kk4);
        float4 bv = *(const float4*)(w_ih + (size_t)(bj * 64 + r) * 256 + k0 + kk4);
        As[kk4 + 0][r] = fmaxf(av.x, 0.f);
        As[kk4 + 1][r] = fmaxf(av.y, 0.f);
        As[kk4 + 2][r] = fmaxf(av.z, 0.f);
        As[kk4 + 3][r] = fmaxf(av.w, 0.f);
        Bs[kk4 + 0][r] = bv.x;
        Bs[kk4 + 1][r] = bv.y;
        Bs[kk4 + 2][r] = bv.z;
        Bs[kk4 + 3][r] = bv.w;
        __syncthreads();
#pragma unroll
        for (int kk = 0; kk < 16; ++kk) {
            float4 a = *(const float4*)&As[kk][ti * 4];
            float4 b = *(const float4*)&Bs[kk][tj * 4];
            acc[0][0] += a.x * b.x; acc[0][1] += a.x * b.y; acc[0][2] += a.x * b.z; acc[0][3] += a.x * b.w;
            acc[1][0] += a.y * b.x; acc[1][1] += a.y * b.y; acc[1][2] += a.y * b.z; acc[1][3] += a.y * b.w;
            acc[2][0] += a.z * b.x; acc[2][1] += a.z * b.y; acc[2][2] += a.z * b.z; acc[2][3] += a.z * b.w;
            acc[3][0] += a.w * b.x; acc[3][1] += a.w * b.y; acc[3][2] += a.w * b.z; acc[3][3] += a.w * b.w;
        }
        __syncthreads();
    }
#pragma unroll
    for (int ii = 0; ii < 4; ++ii) {
        int t = bt * 64 + ti * 4 + ii;
#pragma unroll
        for (int jj = 0; jj < 4; ++jj) {
            int j = bj * 64 + tj * 4 + jj;
            int jp = ((j & 255) << 2) | (j >> 8);
            pre[(size_t)t * 1024 + jp] = acc[ii][jj] + b_ih[j] + b_hh[j];
        }
    }
}

// ---------------------------------------------------------------------------
// Kernel 2a (primary): 4-wave MX-fp6 scan with LDS-only barrier.
// vs round 9: (1) lgkmcnt-only barrier keeps pre loads / hs stores in flight
// across steps; (2) linear e2m3 encoder (bit-identical); (3) depth-4 tree
// select; (4) persistent-zero bq tails; (5) XOR parity offsets.
// ---------------------------------------------------------------------------
__global__ __launch_bounds__(256, 1) void lstm_scan_mx6w4(
    const float* __restrict__ pre,    // (T, 1024), permuted cols 4u+gate
    const unsigned* __restrict__ w6,  // packed fp6 weights
    float* __restrict__ hs)           // (T, 256) fp32
{
    const int tid = threadIdx.x;
    const int w  = tid >> 6;          // wave 0..3
    const int l  = tid & 63;
    const int rto = l & 15;           // owned tile
    const int kg  = l >> 4;           // k-group / unit sub-index
    const float INV = 1.f / 128.f;    // 1/(32*4)

    __shared__ __align__(16) unsigned char h6pk[2][256];  // 8 windows x 32B

    // ---- weights: 16 tiles x 2 kt (unified RF / AGPRs) ----
    i32x8 wA[16][2];
#pragma unroll
    for (int rtt = 0; rtt < 16; ++rtt) {
#pragma unroll
        for (int kt = 0; kt < 2; ++kt) {
            int gt = 16 * w + rtt;
            const unsigned* s = w6 + (size_t)((gt * 2 + kt) * 64 + l) * 8;
            uint4 lo = *(const uint4*)s;
            uint2 hi = *(const uint2*)(s + 4);
            i32x8 v;
            v[0] = (int)lo.x; v[1] = (int)lo.y; v[2] = (int)lo.z;
            v[3] = (int)lo.w; v[4] = (int)hi.x; v[5] = (int)hi.y;
            v[6] = 0; v[7] = 0;
            wA[rtt][kt] = v;
        }
    }

    for (int i = tid; i < 512; i += 256) ((unsigned char*)h6pk)[i] = 0;

    const int u = 64 * w + 4 * rto + kg;                  // owned unit
    float c_st = 0.f;

    // tree-select masks (loop-invariant)
    const bool b0 = (rto & 1), b1 = (rto & 2), b2 = (rto & 4), b3 = (rto & 8);

    // writer-lane constants: wave w packs windows m=2w,2w+1 (48 bytes)
    const bool iswr = (l < 48);
    const int s_  = (l >= 24) ? 1 : 0;
    const int b_  = l - 24 * s_;
    const int j0  = (4 * b_) / 3;
    const int rsh = 8 * b_ - 6 * j0;                      // 0,2,4
    const int j1  = j0 + 1;
    const int lj0 = 16 * (j0 & 3) + 8 * s_ + (j0 >> 2);
    const int lj1 = 16 * (j1 & 3) + 8 * s_ + (j1 >> 2);
    const int wofs = (2 * w + s_) * 32 + b_;

    // parity via XOR'd byte offsets
    int rd_par = 256;                                     // step 0 reads parity 1
    int wr_par = 0;

    // persistent bq tuples: dwords 6,7 stay zero forever
    i32x8 bq0 = (i32x8){0, 0, 0, 0, 0, 0, 0, 0};
    i32x8 bq1 = (i32x8){0, 0, 0, 0, 0, 0, 0, 0};

    f32x4 p4c = *(const f32x4*)(pre + 4 * u);             // t = 0
    const float* pp = pre + 1024 + 4 * u;
    float* hsp = hs + u;
    const unsigned char* h6base = (const unsigned char*)h6pk;
    BAR_LDS();

    for (int t = 0; t < T_LEN; ++t) {
        // prefetch next step's gate bias (stays in flight across the barrier;
        // last iteration reads 16B past pre[] into hs[] scratch - discarded)
        f32x4 p4n = *(const f32x4*)pp;
        pp += 1024;

        // B: packed fp6 windows (kg) and (4+kg), 24B direct reads
        {
            const unsigned char* bp0 = h6base + rd_par + kg * 32;
            uint4 lo = *(const uint4*)bp0;
            uint2 hi = *(const uint2*)(bp0 + 16);
            bq0[0] = (int)lo.x; bq0[1] = (int)lo.y; bq0[2] = (int)lo.z;
            bq0[3] = (int)lo.w; bq0[4] = (int)hi.x; bq0[5] = (int)hi.y;
            const unsigned char* bp1 = bp0 + 128;
            uint4 lo1 = *(const uint4*)bp1;
            uint2 hi1 = *(const uint2*)(bp1 + 16);
            bq1[0] = (int)lo1.x; bq1[1] = (int)lo1.y; bq1[2] = (int)lo1.z;
            bq1[3] = (int)lo1.w; bq1[4] = (int)hi1.x; bq1[5] = (int)hi1.y;
        }

        // MFMA GEMV: 16 tiles x 2 kt; literal-zero C on kt=0
        f32x4 acc[16];
#pragma unroll
        for (int rtt = 0; rtt < 16; ++rtt) {
            acc[rtt] = __builtin_amdgcn_mfma_scale_f32_16x16x128_f8f6f4(
                wA[rtt][0], bq0, (f32x4){0.f, 0.f, 0.f, 0.f},
                2, 2, 0, 0x7f7f7f7f, 0, 0x7f7f7f7f);
            acc[rtt] = __builtin_amdgcn_mfma_scale_f32_16x16x128_f8f6f4(
                wA[rtt][1], bq1, acc[rtt],
                2, 2, 0, 0x7f7f7f7f, 0, 0x7f7f7f7f);
        }

        // depth-4 tree select of owned tile
        f32x4 s0 = b0 ? acc[1]  : acc[0];
        f32x4 s1 = b0 ? acc[3]  : acc[2];
        f32x4 s2 = b0 ? acc[5]  : acc[4];
        f32x4 s3 = b0 ? acc[7]  : acc[6];
        f32x4 s4 = b0 ? acc[9]  : acc[8];
        f32x4 s5 = b0 ? acc[11] : acc[10];
        f32x4 s6 = b0 ? acc[13] : acc[12];
        f32x4 s7 = b0 ? acc[15] : acc[14];
        f32x4 q0 = b1 ? s1 : s0;
        f32x4 q1 = b1 ? s3 : s2;
        f32x4 q2 = b1 ? s5 : s4;
        f32x4 q3 = b1 ? s7 : s6;
        f32x4 r0 = b2 ? q1 : q0;
        f32x4 r1 = b2 ? q3 : q2;
        f32x4 av = b3 ? r1 : r0;

        float gi = fmaf(av.x, INV, p4c.x);
        float gf = fmaf(av.y, INV, p4c.y);
        float gg = fmaf(av.z, INV, p4c.z);
        float go = fmaf(av.w, INV, p4c.w);
        float si = fsig(gi);
        float sf = fsig(gf);
        float tg = 2.f * fsig(2.f * gg) - 1.f;    // tanh, clamp-free
        float so = fsig(go);
        c_st = sf * c_st + si * tg;
        float h = so * (2.f * fsig(2.f * c_st) - 1.f);
        hsp[0] = h;                               // fire-and-forget (no drain)
        hsp += 256;
        int code = enc_e2m3_h4(h);                // bit-identical fast encoder

        // cooperative 6-bit pack: byte b_ of window 2w+s_ from codes j0,j1
        int c0 = __shfl(code, lj0, 64);
        int c1 = __shfl(code, lj1, 64);
        if (iswr) {
            unsigned byte = (((unsigned)c0 >> rsh) | ((unsigned)c1 << (6 - rsh))) & 0xffu;
            *((unsigned char*)h6pk + wr_par + wofs) = (unsigned char)byte;
        }

        p4c = p4n;
        rd_par ^= 256;
        wr_par ^= 256;
        BAR_LDS();
    }
}

// ---------------------------------------------------------------------------
// Kernel 2b (fallback 1): round-8 proven 8-wave MX-fp6 scan (unchanged).
// ---------------------------------------------------------------------------
__global__ __launch_bounds__(512, 2) void lstm_scan_mx6(
    const float* __restrict__ pre,
    const unsigned* __restrict__ w6,
    float* __restrict__ hs)
{
    const int tid = threadIdx.x;
    const int w  = tid >> 6;
    const int l  = tid & 63;
    const int rw = l & 15;
    const int kg = l >> 4;
    const float INV = 1.f / 128.f;

    __shared__ __align__(16) unsigned char h6pk[2][256];
    __shared__ __align__(16) float ldsPre[2][1024];

    i32x8 wA[8][2];
#pragma unroll
    for (int rt = 0; rt < 8; ++rt) {
#pragma unroll
        for (int kt = 0; kt < 2; ++kt) {
            const unsigned* s = w6 + (size_t)(((w * 8 + rt) * 2 + kt) * 64 + l) * 8;
            uint4 lo = *(const uint4*)s;
            uint2 hi = *(const uint2*)(s + 4);
            i32x8 v;
            v[0] = (int)lo.x; v[1] = (int)lo.y; v[2] = (int)lo.z;
            v[3] = (int)lo.w; v[4] = (int)hi.x; v[5] = (int)hi.y;
            v[6] = 0; v[7] = 0;
            wA[rt][kt] = v;
        }
    }

    for (int i = tid; i < 512; i += 512) h6pk[0][i] = 0;
    {
        float2 p = *(const float2*)(pre + 2 * tid);
        *(float2*)&ldsPre[0][2 * tid] = p;
    }

    const bool isup = (rw < 8);
    const int u = 32 * w + 4 * (rw & 7) + kg;
    float c_st = 0.f;

    const bool iswr = (rw < 8) && (kg < 3);
    const int bby = 8 * kg + rw;
    const int j0  = (4 * bby) / 3;
    const int rsh = 8 * bby - 6 * j0;
    const int lj0 = 16 * (j0 & 3) + (j0 >> 2);
    const int j1  = j0 + 1;
    const int lj1 = 16 * (j1 & 3) + (j1 >> 2);

    const float* pnext = pre + 1024 + 2 * tid;
    float* hsp = hs + u;
    __syncthreads();

    for (int t = 0; t < T_LEN; ++t) {
        const int PW = t & 1;
        const int PR = PW ^ 1;

        f32x4 p4 = *(const f32x4*)&ldsPre[PW][4 * u];

        float2 pv = *(const float2*)pnext;
        if (t + 2 < T_LEN) pnext += 1024;

        i32x8 bq[2];
#pragma unroll
        for (int kt = 0; kt < 2; ++kt) {
            const unsigned char* bp = &h6pk[PR][(4 * kt + kg) * 32];
            uint4 lo = *(const uint4*)bp;
            uint2 hi = *(const uint2*)(bp + 16);
            i32x8 b;
            b[0] = (int)lo.x; b[1] = (int)lo.y; b[2] = (int)lo.z; b[3] = (int)lo.w;
            b[4] = (int)hi.x; b[5] = (int)hi.y; b[6] = 0; b[7] = 0;
            bq[kt] = b;
        }

        f32x4 acc[8];
#pragma unroll
        for (int rt = 0; rt < 8; ++rt) acc[rt] = (f32x4){0.f, 0.f, 0.f, 0.f};
#pragma unroll
        for (int rt = 0; rt < 8; ++rt)
#pragma unroll
            for (int kt = 0; kt < 2; ++kt)
                acc[rt] = __builtin_amdgcn_mfma_scale_f32_16x16x128_f8f6f4(
                    wA[rt][kt], bq[kt], acc[rt],
                    2, 2, 0, 0x7f7f7f7f, 0, 0x7f7f7f7f);

        int code = 0;
        if (isup) {
            f32x4 av = acc[0];
            av = (rw == 1) ? acc[1] : av;
            av = (rw == 2) ? acc[2] : av;
            av = (rw == 3) ? acc[3] : av;
            av = (rw == 4) ? acc[4] : av;
            av = (rw == 5) ? acc[5] : av;
            av = (rw == 6) ? acc[6] : av;
            av = (rw == 7) ? acc[7] : av;
            float gi = fmaf(av.x, INV, p4.x);
            float gf = fmaf(av.y, INV, p4.y);
            float gg = fmaf(av.z, INV, p4.z);
            float go = fmaf(av.w, INV, p4.w);
            float si = fsig_c(gi);
            float sf = fsig_c(gf);
            float tg = ftanh_c(gg);
            float so = fsig_c(go);
            c_st = sf * c_st + si * tg;
            float h = so * ftanh_c(c_st);
            hsp[0] = h;
            code = (int)enc_e2m3(h * 4.f);
        }
        hsp += 256;

        int c0 = __shfl(code, lj0, 64);
        int c1 = __shfl(code, lj1, 64);
        if (iswr) {
            unsigned byte = (((unsigned)c0 >> rsh) | ((unsigned)c1 << (6 - rsh))) & 0xffu;
            h6pk[PW][w * 32 + bby] = (unsigned char)byte;
        }

        *(float2*)&ldsPre[PR][2 * tid] = pv;

        __syncthreads();
    }
}

// ---------------------------------------------------------------------------
// Kernel 2c (fallback 2): round-6 proven MX-fp8 scan.
// ---------------------------------------------------------------------------
__global__ __launch_bounds__(512, 2) void lstm_scan_mx8(
    const float* __restrict__ pre,
    const float* __restrict__ w_hh,
    float* __restrict__ hs)
{
    const int tid = threadIdx.x;
    const int w  = tid >> 6;
    const int l  = tid & 63;
    const int rw = l & 15;
    const int kg = l >> 4;
    const float INV = 1.f / 32768.f;

    __shared__ __align__(16) unsigned char h8[2 * 256];
    __shared__ __align__(16) float ldsPre[2][1024];

    i32x8 wA[8][2];
#pragma unroll
    for (int rt = 0; rt < 8; ++rt) {
#pragma unroll
        for (int kt = 0; kt < 2; ++kt) {
            int rowp = ((8 * w + rt) << 4) + rw;
            int orow = ((rowp & 3) << 8) + (rowp >> 2);
            const float* s = w_hh + (size_t)orow * 256 + 128 * kt + 32 * kg;
            i32x8 v;
#pragma unroll
            for (int d = 0; d < 8; ++d) {
                float4 f = *(const float4*)(s + 4 * d);
                v[d] = (int)pk4(f.x * 512.f, f.y * 512.f, f.z * 512.f, f.w * 512.f);
            }
            wA[rt][kt] = v;
        }
    }

    for (int i = tid; i < 512; i += 512) h8[i] = 0;
    {
        float2 p = *(const float2*)(pre + 2 * tid);
        *(float2*)&ldsPre[0][2 * tid] = p;
    }
    float c_st = 0.f;
    const bool isup = (rw < 8);
    const int u = 32 * w + 4 * (rw & 7) + kg;
    const float* pnext = pre + 1024 + 2 * tid;
    float* hsp = hs + u;
    __syncthreads();

    for (int t = 0; t < T_LEN; ++t) {
        const int PW = t & 1;
        const int PR = PW ^ 1;

        f32x4 p4 = *(const f32x4*)&ldsPre[PW][4 * u];

        float2 pv = *(const float2*)pnext;
        if (t + 2 < T_LEN) pnext += 1024;

        i32x8 bq[2];
#pragma unroll
        for (int kt = 0; kt < 2; ++kt) {
            const unsigned char* bp = &h8[PR * 256 + 128 * kt + 32 * kg];
            uint4 lo = *(const uint4*)bp;
            uint4 hi = *(const uint4*)(bp + 16);
            i32x8 b;
            b[0] = (int)lo.x; b[1] = (int)lo.y; b[2] = (int)lo.z; b[3] = (int)lo.w;
            b[4] = (int)hi.x; b[5] = (int)hi.y; b[6] = (int)hi.z; b[7] = (int)hi.w;
            bq[kt] = b;
        }

        f32x4 acc[8];
#pragma unroll
        for (int rt = 0; rt < 8; ++rt) acc[rt] = (f32x4){0.f, 0.f, 0.f, 0.f};
#pragma unroll
        for (int rt = 0; rt < 8; ++rt)
#pragma unroll
            for (int kt = 0; kt < 2; ++kt)
                acc[rt] = __builtin_amdgcn_mfma_scale_f32_16x16x128_f8f6f4(
                    wA[rt][kt], bq[kt], acc[rt],
                    0, 0, 0, 0x7f7f7f7f, 0, 0x7f7f7f7f);

        if (isup) {
            f32x4 av = acc[0];
            av = (rw == 1) ? acc[1] : av;
            av = (rw == 2) ? acc[2] : av;
            av = (rw == 3) ? acc[3] : av;
            av = (rw == 4) ? acc[4] : av;
            av = (rw == 5) ? acc[5] : av;
            av = (rw == 6) ? acc[6] : av;
            av = (rw == 7) ? acc[7] : av;
            float gi = fmaf(av.x, INV, p4.x);
            float gf = fmaf(av.y, INV, p4.y);
            float gg = fmaf(av.z, INV, p4.z);
            float go = fmaf(av.w, INV, p4.w);
            float si = fsig_c(gi);
            float sf = fsig_c(gf);
            float tg = ftanh_c(gg);
            float so = fsig_c(go);
            c_st = sf * c_st + si * tg;
            float h = so * ftanh_c(c_st);
            hsp[0] = h;
            h8[PW * 256 + u] = enc_e4m3(h * 64.f);
        }
        hsp += 256;

        *(float2*)&ldsPre[PR][2 * tid] = pv;

        __syncthreads();
    }
}

// ---------------------------------------------------------------------------
// Kernel 3: conv (FN=128, FL=5) over hs + per-block max over its 64 t's.
// ---------------------------------------------------------------------------
__global__ __launch_bounds__(256) void conv_pool(
    const float* __restrict__ hs,
    const float* __restrict__ cw,
    const float* __restrict__ cb,
    float* __restrict__ part)
{
    __shared__ __align__(16) float hst[68 * 260];
    __shared__ __align__(16) float cwS[128 * 68];
    const int blk = blockIdx.x;
    const int t0 = blk * 64;
    const int tid = threadIdx.x;
    const int i = tid & 15;
    const int g = tid >> 4;

    for (int e = tid; e < 68 * 64; e += 256) {
        int rr = e >> 6;
        int c4 = (e & 63) * 4;
        int tg = t0 + rr; if (tg > 8191) tg = 8191;
        float4 v = *(const float4*)(hs + (size_t)tg * 256 + c4);
        *(float4*)&hst[rr * 260 + c4] = v;
    }

    float acc[4][8];
#pragma unroll
    for (int tt = 0; tt < 4; ++tt)
#pragma unroll
        for (int j = 0; j < 8; ++j) acc[tt][j] = 0.f;

    for (int l = 0; l < 5; ++l) {
        for (int hc = 0; hc < 4; ++hc) {
            __syncthreads();
            {
                int n = tid >> 1;
                int hb = (tid & 1) * 32;
                const float* src = cw + (size_t)n * 1280 + l * 256 + hc * 64 + hb;
                float* dst = &cwS[n * 68 + hb];
#pragma unroll
                for (int q = 0; q < 8; ++q) {
                    float4 v = *(const float4*)(src + 4 * q);
                    *(float4*)(dst + 4 * q) = v;
                }
            }
            __syncthreads();
#pragma unroll 4
            for (int q = 0; q < 16; ++q) {
                float4 hvv[4];
#pragma unroll
                for (int tt = 0; tt < 4; ++tt)
                    hvv[tt] = *(const float4*)&hst[(i + 16 * tt + l) * 260 + hc * 64 + 4 * q];
#pragma unroll
                for (int j = 0; j < 8; ++j) {
                    float4 wv = *(const float4*)&cwS[(g + 16 * j) * 68 + 4 * q];
#pragma unroll
                    for (int tt = 0; tt < 4; ++tt) {
                        acc[tt][j] += hvv[tt].x * wv.x + hvv[tt].y * wv.y
                                    + hvv[tt].z * wv.z + hvv[tt].w * wv.w;
                    }
                }
            }
        }
    }

    float m[8];
#pragma unroll
    for (int j = 0; j < 8; ++j) {
        int n = g + 16 * j;
        float cbn = cb[n];
        float mm = -INFINITY;
#pragma unroll
        for (int tt = 0; tt < 4; ++tt) {
            int t = t0 + i + 16 * tt;
            float v = acc[tt][j] + cbn;
            if (t < 8188) mm = fmaxf(mm, v);
        }
        mm = DPP_MAX(mm, 0xB1);
        mm = DPP_MAX(mm, 0x4E);
        mm = DPP_MAX(mm, 0x141);
        mm = DPP_MAX(mm, 0x140);
        m[j] = mm;
    }
    if (i == 0) {
#pragma unroll
        for (int j = 0; j < 8; ++j)
            part[(size_t)blk * 128 + g + 16 * j] = m[j];
    }
}

// ---------------------------------------------------------------------------
// Kernel 4: final head — pool-reduce, logits, log_softmax, loss + acc.
// ---------------------------------------------------------------------------
__global__ void final_head(
    const float* __restrict__ part,
    const float* __restrict__ logits_w,
    const float* __restrict__ logits_b,
    const int* __restrict__ labels,
    float* __restrict__ out)
{
    __shared__ float pooled[128];
    __shared__ float lgt[20];
    int tid = threadIdx.x;
    float mx = -INFINITY;
    for (int b = 0; b < 128; ++b) mx = fmaxf(mx, part[(size_t)b * 128 + tid]);
    pooled[tid] = mx;
    __syncthreads();
    if (tid < 20) {
        float s = logits_b[tid];
        for (int k = 0; k < 128; ++k) s += logits_w[tid * 128 + k] * pooled[k];
        lgt[tid] = s;
    }
    __syncthreads();
    if (tid == 0) {
        float m = lgt[0]; int am = 0;
        for (int c2 = 1; c2 < 20; ++c2) { if (lgt[c2] > m) { m = lgt[c2]; am = c2; } }
        float se = 0.f;
        for (int c2 = 0; c2 < 20; ++c2) se += expf(lgt[c2] - m);
        float lse = m + logf(se);
        int lbl = labels[0];
        out[0] = -(lgt[lbl] - lse);
        out[1] = (am == lbl) ? 1.f : 0.f;
    }
}

// ---------------------------------------------------------------------------
extern "C" void kernel_launch(void* const* d_in, const int* in_sizes, int n_in,
                              void* d_out, int out_size, void* d_ws, size_t ws_size,
                              hipStream_t stream) {
    (void)in_sizes; (void)n_in; (void)out_size;
    const int*   docs   = (const int*)d_in[0];
    const int*   labels = (const int*)d_in[2];
    const float* embW   = (const float*)d_in[4];
    const float* w_ih   = (const float*)d_in[5];
    const float* w_hh   = (const float*)d_in[6];
    const float* b_ih   = (const float*)d_in[7];
    const float* b_hh   = (const float*)d_in[8];
    const float* cw     = (const float*)d_in[9];
    const float* cb     = (const float*)d_in[10];
    const float* lw     = (const float*)d_in[11];
    const float* lb     = (const float*)d_in[12];
    float* out = (float*)d_out;

    char* ws = (char*)d_ws;
    float*    pre  = (float*)(ws);                 // 33554432 B
    float*    hs   = (float*)(ws + 33554432);      //  8388608 B
    float*    part = (float*)(ws + 41943040);      //    65536 B
    unsigned* w6   = (unsigned*)(ws + 42008576);   //   262144 B

    bool ws_ok = (ws_size >= (size_t)42270720);
    hipFuncAttributes a4, a6;
    bool ok4 = ws_ok
        && (hipFuncGetAttributes(&a4, (const void*)lstm_scan_mx6w4) == hipSuccess)
        && (a4.localSizeBytes == 0);
    bool ok6 = ws_ok
        && (hipFuncGetAttributes(&a6, (const void*)lstm_scan_mx6) == hipSuccess)
        && (a6.localSizeBytes == 0);

    gemm_pre<<<dim3(128, 16, 1), 256, 0, stream>>>(docs, embW, w_ih, b_ih, b_hh, pre);
    if (ok4 || ok6) {
        pack_w6<<<32, 256, 0, stream>>>(w_hh, w6);
        if (ok4) lstm_scan_mx6w4<<<1, 256, 0, stream>>>(pre, w6, hs);
        else     lstm_scan_mx6<<<1, 512, 0, stream>>>(pre, w6, hs);
    } else {
        lstm_scan_mx8<<<1, 512, 0, stream>>>(pre, w_hh, hs);
    }
    conv_pool<<<128, 256, 0, stream>>>(hs, cw, cb, part);
    final_head<<<1, 128, 0, stream>>>(part, lw, lb, labels, out);
}

// Round 12
// 5518.687 us; speedup vs baseline: 1.1251x; 1.0793x over previous
//
#include <hip/hip_runtime.h>
#include <math.h>

#define T_LEN 8192

typedef float f32x4 __attribute__((ext_vector_type(4)));
typedef int   i32x8 __attribute__((ext_vector_type(8)));
typedef int   i32x6 __attribute__((ext_vector_type(6)));   // fp6 operand tuple

#define DPP_MAX(x, ctrl) fmaxf((x), __int_as_float(__builtin_amdgcn_update_dpp(0, __float_as_int(x), (ctrl), 0xF, 0xF, true)))

// LDS-only barrier: drain LDS ops, leave global loads/stores in flight.
#define BAR_LDS() do { \
    __builtin_amdgcn_sched_barrier(0); \
    asm volatile("s_waitcnt lgkmcnt(0)" ::: "memory"); \
    __builtin_amdgcn_s_barrier(); \
    __builtin_amdgcn_sched_barrier(0); \
} while (0)

__device__ __forceinline__ float fexp2(float x) {
#if __has_builtin(__builtin_amdgcn_exp2f)
    return __builtin_amdgcn_exp2f(x);
#else
    return exp2f(x);
#endif
}
__device__ __forceinline__ float rcp1p(float e) {
    return __builtin_amdgcn_rcpf(1.f + e);
}
__device__ __forceinline__ float fsig_c(float x) {
    x = fminf(30.f, fmaxf(-30.f, x));
    float e = __expf(-x);
    return __builtin_amdgcn_rcpf(1.f + e);
}
__device__ __forceinline__ float ftanh_c(float x) {
    x = fminf(15.f, fmaxf(-15.f, x));
    float e = __expf(-2.f * x);
    return (1.f - e) * __builtin_amdgcn_rcpf(1.f + e);
}

// ---- OCP e4m3fn encode ----
__device__ __forceinline__ unsigned char enc_e4m3(float x) {
#if __has_builtin(__builtin_amdgcn_cvt_pk_fp8_f32)
    int v = __builtin_amdgcn_cvt_pk_fp8_f32(x, 0.f, 0, false);
    return (unsigned char)(v & 0xff);
#else
    unsigned u = __float_as_uint(x);
    unsigned s = (u >> 24) & 0x80u;
    float a = fabsf(x);
    if (a > 448.f) a = 448.f;
    if (a < 9.765625e-4f) return (unsigned char)s;
    int e = ((int)((__float_as_uint(a) >> 23) & 0xffu)) - 127;
    int eu = e < -6 ? -6 : e;
    float ulp = exp2f((float)(eu - 3));
    float q = rintf(a / ulp);
    int mant, ee;
    if (eu == -6 && q < 8.f) { mant = (int)q; ee = 0; }
    else {
        if (q >= 16.f) { q *= 0.5f; eu += 1; }
        mant = (int)q - 8; ee = eu + 7;
        if (ee > 15 || (ee == 15 && mant > 6)) { ee = 15; mant = 6; }
    }
    return (unsigned char)(s | (unsigned)(ee << 3) | (unsigned)mant);
#endif
}
__device__ __forceinline__ unsigned pk4(float a, float b, float c, float d) {
    return (unsigned)enc_e4m3(a) | ((unsigned)enc_e4m3(b) << 8)
         | ((unsigned)enc_e4m3(c) << 16) | ((unsigned)enc_e4m3(d) << 24);
}

// ---- OCP e2m3 (fp6) encode: full version (pre-pass only) ----
__device__ __forceinline__ unsigned enc_e2m3(float x) {
    unsigned s = (__float_as_uint(x) >> 31) << 5;
    float a = fabsf(x);
    a = fminf(a, 7.5f);
    if (a < 0.0625f) return s;
    int e = ((int)((__float_as_uint(a) >> 23) & 0xffu)) - 127;
    int eu = e < 0 ? 0 : e;
    float ulp = __int_as_float((unsigned)(eu + 124) << 23);     // 2^(eu-3)
    float q = rintf(a * __builtin_amdgcn_rcpf(ulp));
    int E, M;
    if (e < 0) {
        if (q >= 8.f) { E = 1; M = 0; }
        else { E = 0; M = (int)q; }
    } else {
        if (q >= 16.f) { q = 8.f; eu += 1; }
        if (eu > 2) { E = 3; M = 7; }
        else { E = eu + 1; M = (int)q - 8; }
    }
    return s | (unsigned)(E << 3) | (unsigned)M;
}

// ---- fast e2m3 for |h|<1 (a=4|h|<4): piecewise-linear, bit-identical ----
__device__ __forceinline__ int enc_e2m3_h4(float h) {
    float x = h * 4.f;
    float a = fabsf(x);
    int c1 = (int)rintf(a * 8.f);
    int c2 = (int)rintf(a * 4.f) + 8;
    int mag = (a < 2.f) ? c1 : c2;
    return mag | (int)((__float_as_uint(h) >> 26) & 32u);
}

// ---------------------------------------------------------------------------
// Kernel 0: one-shot pre-pass — quantize W_hh to packed fp6 (e2m3, x32).
// ---------------------------------------------------------------------------
__global__ __launch_bounds__(256) void pack_w6(
    const float* __restrict__ w_hh,   // (1024, 256)
    unsigned* __restrict__ w6)        // 8192 items x 8 dwords (6 used)
{
    int idx = blockIdx.x * 256 + threadIdx.x;   // 0..8191
    int l  = idx & 63;
    int kt = (idx >> 6) & 1;
    int gt = idx >> 7;                            // 0..63
    int rw = l & 15, kg = l >> 4;
    int rowp = (gt << 4) + rw;                    // permuted row 4u+gate
    int orow = ((rowp & 3) << 8) + (rowp >> 2);   // original gate-major row
    const float* s = w_hh + (size_t)orow * 256 + 128 * kt + 32 * kg;
    unsigned d[6] = {0, 0, 0, 0, 0, 0};
#pragma unroll
    for (int j = 0; j < 32; ++j) {
        unsigned c = enc_e2m3(s[j] * 32.f);
        int bit = 6 * j;
        d[bit >> 5] |= c << (bit & 31);
        if ((bit & 31) > 26) d[(bit >> 5) + 1] |= c >> (32 - (bit & 31));
    }
    unsigned* o = w6 + (size_t)idx * 8;
    o[0] = d[0]; o[1] = d[1]; o[2] = d[2];
    o[3] = d[3]; o[4] = d[4]; o[5] = d[5];
    o[6] = 0;    o[7] = 0;
}

// ---------------------------------------------------------------------------
// Kernel 1: pre = relu(embed_W[docs]) @ w_ih^T + (b_ih + b_hh)   (T x 1024)
// Output columns PERMUTED: col' = 4*unit + gate
// ---------------------------------------------------------------------------
__global__ __launch_bounds__(256, 4) void gemm_pre(
    const int* __restrict__ docs,
    const float* __restrict__ embW,
    const float* __restrict__ w_ih,
    const float* __restrict__ b_ih,
    const float* __restrict__ b_hh,
    float* __restrict__ pre)
{
    __shared__ __align__(16) float As[16][68];
    __shared__ __align__(16) float Bs[16][68];
    __shared__ int rowid[64];
    const int bt = blockIdx.x;
    const int bj = blockIdx.y;
    const int tid = threadIdx.x;
    if (tid < 64) rowid[tid] = docs[bt * 64 + tid];
    __syncthreads();
    const int ti = tid & 15, tj = tid >> 4;
    const int r = tid & 63;
    const int kk4 = (tid >> 6) * 4;
    float acc[4][4];
#pragma unroll
    for (int ii = 0; ii < 4; ++ii)
#pragma unroll
        for (int jj = 0; jj < 4; ++jj) acc[ii][jj] = 0.f;

    for (int k0 = 0; k0 < 256; k0 += 16) {
        float4 av = *(const float4*)(embW + (size_t)rowid[r] * 256 + k0 + kk4);
        float4 bv = *(const float4*)(w_ih + (size_t)(bj * 64 + r) * 256 + k0 + kk4);
        As[kk4 + 0][r] = fmaxf(av.x, 0.f);
        As[kk4 + 1][r] = fmaxf(av.y, 0.f);
        As[kk4 + 2][r] = fmaxf(av.z, 0.f);
        As[kk4 + 3][r] = fmaxf(av.w, 0.f);
        Bs[kk4 + 0][r] = bv.x;
        Bs[kk4 + 1][r] = bv.y;
        Bs[kk4 + 2][r] = bv.z;
        Bs[kk4 + 3][r] = bv.w;
        __syncthreads();
#pragma unroll
        for (int kk = 0; kk < 16; ++kk) {
            float4 a = *(const float4*)&As[kk][ti * 4];
            float4 b = *(const float4*)&Bs[kk][tj * 4];
            acc[0][0] += a.x * b.x; acc[0][1] += a.x * b.y; acc[0][2] += a.x * b.z; acc[0][3] += a.x * b.w;
            acc[1][0] += a.y * b.x; acc[1][1] += a.y * b.y; acc[1][2] += a.y * b.z; acc[1][3] += a.y * b.w;
            acc[2][0] += a.z * b.x; acc[2][1] += a.z * b.y; acc[2][2] += a.z * b.z; acc[2][3] += a.z * b.w;
            acc[3][0] += a.w * b.x; acc[3][1] += a.w * b.y; acc[3][2] += a.w * b.z; acc[3][3] += a.w * b.w;
        }
        __syncthreads();
    }
#pragma unroll
    for (int ii = 0; ii < 4; ++ii) {
        int t = bt * 64 + ti * 4 + ii;
#pragma unroll
        for (int jj = 0; jj < 4; ++jj) {
            int j = bj * 64 + tj * 4 + jj;
            int jp = ((j & 255) << 2) | (j >> 8);
            pre[(size_t)t * 1024 + jp] = acc[ii][jj] + b_ih[j] + b_hh[j];
        }
    }
}

// one asm statement per tile: kt=0 (C = pinned zero) chained into kt=1.
// fp6 (cbsz/blgp=2) requires 6-register tuples; A direct from AGPRs.
#define MFMA_PAIR(RT, DST) \
    asm("v_mfma_scale_f32_16x16x128_f8f6f4 %0, %1, %2, %5, %6, %6 cbsz:2 blgp:2\n\t" \
        "v_mfma_scale_f32_16x16x128_f8f6f4 %0, %3, %4, %0, %6, %6 cbsz:2 blgp:2" \
        : "=&v"(DST) \
        : "a"(wA[RT][0]), "v"(bq0), "a"(wA[RT][1]), "v"(bq1), "v"(CZ), "v"(sc))

// ---------------------------------------------------------------------------
// Kernel 2a (primary): 4-wave MX-fp6 scan, inline-asm MFMA, A from AGPRs.
// ---------------------------------------------------------------------------
__global__ __launch_bounds__(256, 1) void lstm_scan_mx6a(
    const float* __restrict__ pre,    // (T, 1024), permuted cols 4u+gate
    const unsigned* __restrict__ w6,  // packed fp6 weights
    float* __restrict__ hs)           // (T, 256) fp32
{
    const int tid = threadIdx.x;
    const int w  = tid >> 6;          // wave 0..3
    const int l  = tid & 63;
    const int rto = l & 15;           // owned tile
    const int kg  = l >> 4;           // k-group / unit sub-index
    const float C_L2E  = -1.4426950408889634f;   // -log2(e)
    const float C_L2E2 = -2.8853900817779268f;   // -2*log2(e)
    const float I_L2E  = C_L2E  / 128.f;         // fold INV=1/128
    const float I_L2E2 = C_L2E2 / 128.f;

    __shared__ __align__(32) unsigned char h6pk[2][256];  // 8 windows x 32B

    // ---- weights: 16 tiles x 2 kt as 6-dword fp6 tuples (AGPR-resident) ----
    i32x6 wA[16][2];
#pragma unroll
    for (int rtt = 0; rtt < 16; ++rtt) {
#pragma unroll
        for (int kt = 0; kt < 2; ++kt) {
            int gt = 16 * w + rtt;
            const unsigned* s = w6 + (size_t)((gt * 2 + kt) * 64 + l) * 8;
            uint4 lo = *(const uint4*)s;
            uint2 hi = *(const uint2*)(s + 4);
            i32x6 v;
            v[0] = (int)lo.x; v[1] = (int)lo.y; v[2] = (int)lo.z;
            v[3] = (int)lo.w; v[4] = (int)hi.x; v[5] = (int)hi.y;
            wA[rtt][kt] = v;
        }
    }

    for (int i = tid; i < 512; i += 256) ((unsigned char*)h6pk)[i] = 0;

    const int u = 64 * w + 4 * rto + kg;                  // owned unit
    float c_st = 0.f;

    const bool b0 = (rto & 1), b1 = (rto & 2), b2 = (rto & 4), b3 = (rto & 8);

    // writer-lane constants: wave w packs windows 2w, 2w+1 (48 bytes)
    const bool iswr = (l < 48);
    const int s_  = (l >= 24) ? 1 : 0;
    const int b_  = l - 24 * s_;
    const int j0  = (4 * b_) / 3;
    const int rsh = 8 * b_ - 6 * j0;                      // 0,2,4
    const int j1  = j0 + 1;
    const int lj0 = 16 * (j0 & 3) + 8 * s_ + (j0 >> 2);
    const int lj1 = 16 * (j1 & 3) + 8 * s_ + (j1 >> 2);
    const int wofs = (2 * w + s_) * 32 + b_;

    f32x4 CZ = (f32x4){0.f, 0.f, 0.f, 0.f};
    asm("" : "+v"(CZ));                                   // pin zero tuple
    int sc = 0x7f7f7f7f;                                  // e8m0 scale = 1.0

    f32x4 p4c = *(const f32x4*)(pre + 4 * u);             // t = 0
    float tx = p4c.x * C_L2E;
    float ty = p4c.y * C_L2E;
    float tz = p4c.z * C_L2E2;
    float tw = p4c.w * C_L2E;
    const float* pp = pre + 1024 + 4 * u;
    float* hsp = hs + u;
    const unsigned char* h6base = (const unsigned char*)h6pk;
    BAR_LDS();

#define LSTM_STEP(RD, WR) do { \
    f32x4 p4n = *(const f32x4*)pp; pp += 1024; \
    i32x6 bq0, bq1; \
    { \
        const unsigned char* bp0 = h6base + (RD) + kg * 32; \
        uint4 lo = *(const uint4*)bp0; \
        uint2 hi = *(const uint2*)(bp0 + 16); \
        bq0[0] = (int)lo.x; bq0[1] = (int)lo.y; bq0[2] = (int)lo.z; \
        bq0[3] = (int)lo.w; bq0[4] = (int)hi.x; bq0[5] = (int)hi.y; \
        const unsigned char* bp1 = bp0 + 128; \
        uint4 lo1 = *(const uint4*)bp1; \
        uint2 hi1 = *(const uint2*)(bp1 + 16); \
        bq1[0] = (int)lo1.x; bq1[1] = (int)lo1.y; bq1[2] = (int)lo1.z; \
        bq1[3] = (int)lo1.w; bq1[4] = (int)hi1.x; bq1[5] = (int)hi1.y; \
    } \
    f32x4 a0, a1, a2, a3, a4, a5, a6, a7, a8, a9, a10, a11, a12, a13, a14, a15; \
    MFMA_PAIR(0, a0);  MFMA_PAIR(1, a1);  MFMA_PAIR(2, a2);  MFMA_PAIR(3, a3); \
    MFMA_PAIR(4, a4);  MFMA_PAIR(5, a5);  MFMA_PAIR(6, a6);  MFMA_PAIR(7, a7); \
    MFMA_PAIR(8, a8);  MFMA_PAIR(9, a9);  MFMA_PAIR(10, a10); MFMA_PAIR(11, a11); \
    MFMA_PAIR(12, a12); MFMA_PAIR(13, a13); MFMA_PAIR(14, a14); MFMA_PAIR(15, a15); \
    asm volatile("s_nop 7\n\ts_nop 7\n\ts_nop 7" \
        : "+v"(a0), "+v"(a1), "+v"(a2), "+v"(a3), "+v"(a4), "+v"(a5), "+v"(a6), "+v"(a7), \
          "+v"(a8), "+v"(a9), "+v"(a10), "+v"(a11), "+v"(a12), "+v"(a13), "+v"(a14), "+v"(a15)); \
    f32x4 s0 = b0 ? a1  : a0; \
    f32x4 s1 = b0 ? a3  : a2; \
    f32x4 s2 = b0 ? a5  : a4; \
    f32x4 s3 = b0 ? a7  : a6; \
    f32x4 s4 = b0 ? a9  : a8; \
    f32x4 s5 = b0 ? a11 : a10; \
    f32x4 s6 = b0 ? a13 : a12; \
    f32x4 s7 = b0 ? a15 : a14; \
    f32x4 q0 = b1 ? s1 : s0; \
    f32x4 q1 = b1 ? s3 : s2; \
    f32x4 q2 = b1 ? s5 : s4; \
    f32x4 q3 = b1 ? s7 : s6; \
    f32x4 r0 = b2 ? q1 : q0; \
    f32x4 r1 = b2 ? q3 : q2; \
    f32x4 av = b3 ? r1 : r0; \
    float nx = p4n.x * C_L2E, ny = p4n.y * C_L2E; \
    float nz = p4n.z * C_L2E2, nw = p4n.w * C_L2E; \
    float si = rcp1p(fexp2(fmaf(av.x, I_L2E,  tx))); \
    float sf = rcp1p(fexp2(fmaf(av.y, I_L2E,  ty))); \
    float tg = 2.f * rcp1p(fexp2(fmaf(av.z, I_L2E2, tz))) - 1.f; \
    float so = rcp1p(fexp2(fmaf(av.w, I_L2E,  tw))); \
    c_st = sf * c_st + si * tg; \
    float h = so * (2.f * rcp1p(fexp2(c_st * C_L2E2)) - 1.f); \
    hsp[0] = h; hsp += 256; \
    int code = enc_e2m3_h4(h); \
    int c0 = __shfl(code, lj0, 64); \
    int c1 = __shfl(code, lj1, 64); \
    if (iswr) { \
        unsigned byte = (((unsigned)c0 >> rsh) | ((unsigned)c1 << (6 - rsh))) & 0xffu; \
        *((unsigned char*)h6pk + (WR) + wofs) = (unsigned char)byte; \
    } \
    tx = nx; ty = ny; tz = nz; tw = nw; \
    BAR_LDS(); \
} while (0)

    for (int t2 = 0; t2 < T_LEN; t2 += 2) {
        LSTM_STEP(256, 0);    // even step: read parity 1, write parity 0
        LSTM_STEP(0, 256);    // odd step: read parity 0, write parity 1
    }
#undef LSTM_STEP
}

// ---------------------------------------------------------------------------
// Kernel 2b (fallback 1): round-8 proven 8-wave MX-fp6 scan (builtin).
// ---------------------------------------------------------------------------
__global__ __launch_bounds__(512, 2) void lstm_scan_mx6(
    const float* __restrict__ pre,
    const unsigned* __restrict__ w6,
    float* __restrict__ hs)
{
    const int tid = threadIdx.x;
    const int w  = tid >> 6;
    const int l  = tid & 63;
    const int rw = l & 15;
    const int kg = l >> 4;
    const float INV = 1.f / 128.f;

    __shared__ __align__(16) unsigned char h6pk[2][256];
    __shared__ __align__(16) float ldsPre[2][1024];

    i32x8 wA[8][2];
#pragma unroll
    for (int rt = 0; rt < 8; ++rt) {
#pragma unroll
        for (int kt = 0; kt < 2; ++kt) {
            const unsigned* s = w6 + (size_t)(((w * 8 + rt) * 2 + kt) * 64 + l) * 8;
            uint4 lo = *(const uint4*)s;
            uint2 hi = *(const uint2*)(s + 4);
            i32x8 v;
            v[0] = (int)lo.x; v[1] = (int)lo.y; v[2] = (int)lo.z;
            v[3] = (int)lo.w; v[4] = (int)hi.x; v[5] = (int)hi.y;
            v[6] = 0; v[7] = 0;
            wA[rt][kt] = v;
        }
    }

    for (int i = tid; i < 512; i += 512) h6pk[0][i] = 0;
    {
        float2 p = *(const float2*)(pre + 2 * tid);
        *(float2*)&ldsPre[0][2 * tid] = p;
    }

    const bool isup = (rw < 8);
    const int u = 32 * w + 4 * (rw & 7) + kg;
    float c_st = 0.f;

    const bool iswr = (rw < 8) && (kg < 3);
    const int bby = 8 * kg + rw;
    const int j0  = (4 * bby) / 3;
    const int rsh = 8 * bby - 6 * j0;
    const int lj0 = 16 * (j0 & 3) + (j0 >> 2);
    const int j1  = j0 + 1;
    const int lj1 = 16 * (j1 & 3) + (j1 >> 2);

    const float* pnext = pre + 1024 + 2 * tid;
    float* hsp = hs + u;
    __syncthreads();

    for (int t = 0; t < T_LEN; ++t) {
        const int PW = t & 1;
        const int PR = PW ^ 1;

        f32x4 p4 = *(const f32x4*)&ldsPre[PW][4 * u];

        float2 pv = *(const float2*)pnext;
        if (t + 2 < T_LEN) pnext += 1024;

        i32x8 bq[2];
#pragma unroll
        for (int kt = 0; kt < 2; ++kt) {
            const unsigned char* bp = &h6pk[PR][(4 * kt + kg) * 32];
            uint4 lo = *(const uint4*)bp;
            uint2 hi = *(const uint2*)(bp + 16);
            i32x8 b;
            b[0] = (int)lo.x; b[1] = (int)lo.y; b[2] = (int)lo.z; b[3] = (int)lo.w;
            b[4] = (int)hi.x; b[5] = (int)hi.y; b[6] = 0; b[7] = 0;
            bq[kt] = b;
        }

        f32x4 acc[8];
#pragma unroll
        for (int rt = 0; rt < 8; ++rt) acc[rt] = (f32x4){0.f, 0.f, 0.f, 0.f};
#pragma unroll
        for (int rt = 0; rt < 8; ++rt)
#pragma unroll
            for (int kt = 0; kt < 2; ++kt)
                acc[rt] = __builtin_amdgcn_mfma_scale_f32_16x16x128_f8f6f4(
                    wA[rt][kt], bq[kt], acc[rt],
                    2, 2, 0, 0x7f7f7f7f, 0, 0x7f7f7f7f);

        int code = 0;
        if (isup) {
            f32x4 av = acc[0];
            av = (rw == 1) ? acc[1] : av;
            av = (rw == 2) ? acc[2] : av;
            av = (rw == 3) ? acc[3] : av;
            av = (rw == 4) ? acc[4] : av;
            av = (rw == 5) ? acc[5] : av;
            av = (rw == 6) ? acc[6] : av;
            av = (rw == 7) ? acc[7] : av;
            float gi = fmaf(av.x, INV, p4.x);
            float gf = fmaf(av.y, INV, p4.y);
            float gg = fmaf(av.z, INV, p4.z);
            float go = fmaf(av.w, INV, p4.w);
            float si = fsig_c(gi);
            float sf = fsig_c(gf);
            float tg = ftanh_c(gg);
            float so = fsig_c(go);
            c_st = sf * c_st + si * tg;
            float h = so * ftanh_c(c_st);
            hsp[0] = h;
            code = (int)enc_e2m3(h * 4.f);
        }
        hsp += 256;

        int c0 = __shfl(code, lj0, 64);
        int c1 = __shfl(code, lj1, 64);
        if (iswr) {
            unsigned byte = (((unsigned)c0 >> rsh) | ((unsigned)c1 << (6 - rsh))) & 0xffu;
            h6pk[PW][w * 32 + bby] = (unsigned char)byte;
        }

        *(float2*)&ldsPre[PR][2 * tid] = pv;

        __syncthreads();
    }
}

// ---------------------------------------------------------------------------
// Kernel 2c (fallback 2): round-6 proven MX-fp8 scan.
// ---------------------------------------------------------------------------
__global__ __launch_bounds__(512, 2) void lstm_scan_mx8(
    const float* __restrict__ pre,
    const float* __restrict__ w_hh,
    float* __restrict__ hs)
{
    const int tid = threadIdx.x;
    const int w  = tid >> 6;
    const int l  = tid & 63;
    const int rw = l & 15;
    const int kg = l >> 4;
    const float INV = 1.f / 32768.f;

    __shared__ __align__(16) unsigned char h8[2 * 256];
    __shared__ __align__(16) float ldsPre[2][1024];

    i32x8 wA[8][2];
#pragma unroll
    for (int rt = 0; rt < 8; ++rt) {
#pragma unroll
        for (int kt = 0; kt < 2; ++kt) {
            int rowp = ((8 * w + rt) << 4) + rw;
            int orow = ((rowp & 3) << 8) + (rowp >> 2);
            const float* s = w_hh + (size_t)orow * 256 + 128 * kt + 32 * kg;
            i32x8 v;
#pragma unroll
            for (int d = 0; d < 8; ++d) {
                float4 f = *(const float4*)(s + 4 * d);
                v[d] = (int)pk4(f.x * 512.f, f.y * 512.f, f.z * 512.f, f.w * 512.f);
            }
            wA[rt][kt] = v;
        }
    }

    for (int i = tid; i < 512; i += 512) h8[i] = 0;
    {
        float2 p = *(const float2*)(pre + 2 * tid);
        *(float2*)&ldsPre[0][2 * tid] = p;
    }
    float c_st = 0.f;
    const bool isup = (rw < 8);
    const int u = 32 * w + 4 * (rw & 7) + kg;
    const float* pnext = pre + 1024 + 2 * tid;
    float* hsp = hs + u;
    __syncthreads();

    for (int t = 0; t < T_LEN; ++t) {
        const int PW = t & 1;
        const int PR = PW ^ 1;

        f32x4 p4 = *(const f32x4*)&ldsPre[PW][4 * u];

        float2 pv = *(const float2*)pnext;
        if (t + 2 < T_LEN) pnext += 1024;

        i32x8 bq[2];
#pragma unroll
        for (int kt = 0; kt < 2; ++kt) {
            const unsigned char* bp = &h8[PR * 256 + 128 * kt + 32 * kg];
            uint4 lo = *(const uint4*)bp;
            uint4 hi = *(const uint4*)(bp + 16);
            i32x8 b;
            b[0] = (int)lo.x; b[1] = (int)lo.y; b[2] = (int)lo.z; b[3] = (int)lo.w;
            b[4] = (int)hi.x; b[5] = (int)hi.y; b[6] = (int)hi.z; b[7] = (int)hi.w;
            bq[kt] = b;
        }

        f32x4 acc[8];
#pragma unroll
        for (int rt = 0; rt < 8; ++rt) acc[rt] = (f32x4){0.f, 0.f, 0.f, 0.f};
#pragma unroll
        for (int rt = 0; rt < 8; ++rt)
#pragma unroll
            for (int kt = 0; kt < 2; ++kt)
                acc[rt] = __builtin_amdgcn_mfma_scale_f32_16x16x128_f8f6f4(
                    wA[rt][kt], bq[kt], acc[rt],
                    0, 0, 0, 0x7f7f7f7f, 0, 0x7f7f7f7f);

        if (isup) {
            f32x4 av = acc[0];
            av = (rw == 1) ? acc[1] : av;
            av = (rw == 2) ? acc[2] : av;
            av = (rw == 3) ? acc[3] : av;
            av = (rw == 4) ? acc[4] : av;
            av = (rw == 5) ? acc[5] : av;
            av = (rw == 6) ? acc[6] : av;
            av = (rw == 7) ? acc[7] : av;
            float gi = fmaf(av.x, INV, p4.x);
            float gf = fmaf(av.y, INV, p4.y);
            float gg = fmaf(av.z, INV, p4.z);
            float go = fmaf(av.w, INV, p4.w);
            float si = fsig_c(gi);
            float sf = fsig_c(gf);
            float tg = ftanh_c(gg);
            float so = fsig_c(go);
            c_st = sf * c_st + si * tg;
            float h = so * ftanh_c(c_st);
            hsp[0] = h;
            h8[PW * 256 + u] = enc_e4m3(h * 64.f);
        }
        hsp += 256;

        *(float2*)&ldsPre[PR][2 * tid] = pv;

        __syncthreads();
    }
}

// ---------------------------------------------------------------------------
// Kernel 3: conv (FN=128, FL=5) over hs + per-block max over its 64 t's.
// ---------------------------------------------------------------------------
__global__ __launch_bounds__(256) void conv_pool(
    const float* __restrict__ hs,
    const float* __restrict__ cw,
    const float* __restrict__ cb,
    float* __restrict__ part)
{
    __shared__ __align__(16) float hst[68 * 260];
    __shared__ __align__(16) float cwS[128 * 68];
    const int blk = blockIdx.x;
    const int t0 = blk * 64;
    const int tid = threadIdx.x;
    const int i = tid & 15;
    const int g = tid >> 4;

    for (int e = tid; e < 68 * 64; e += 256) {
        int rr = e >> 6;
        int c4 = (e & 63) * 4;
        int tg = t0 + rr; if (tg > 8191) tg = 8191;
        float4 v = *(const float4*)(hs + (size_t)tg * 256 + c4);
        *(float4*)&hst[rr * 260 + c4] = v;
    }

    float acc[4][8];
#pragma unroll
    for (int tt = 0; tt < 4; ++tt)
#pragma unroll
        for (int j = 0; j < 8; ++j) acc[tt][j] = 0.f;

    for (int l = 0; l < 5; ++l) {
        for (int hc = 0; hc < 4; ++hc) {
            __syncthreads();
            {
                int n = tid >> 1;
                int hb = (tid & 1) * 32;
                const float* src = cw + (size_t)n * 1280 + l * 256 + hc * 64 + hb;
                float* dst = &cwS[n * 68 + hb];
#pragma unroll
                for (int q = 0; q < 8; ++q) {
                    float4 v = *(const float4*)(src + 4 * q);
                    *(float4*)(dst + 4 * q) = v;
                }
            }
            __syncthreads();
#pragma unroll 4
            for (int q = 0; q < 16; ++q) {
                float4 hvv[4];
#pragma unroll
                for (int tt = 0; tt < 4; ++tt)
                    hvv[tt] = *(const float4*)&hst[(i + 16 * tt + l) * 260 + hc * 64 + 4 * q];
#pragma unroll
                for (int j = 0; j < 8; ++j) {
                    float4 wv = *(const float4*)&cwS[(g + 16 * j) * 68 + 4 * q];
#pragma unroll
                    for (int tt = 0; tt < 4; ++tt) {
                        acc[tt][j] += hvv[tt].x * wv.x + hvv[tt].y * wv.y
                                    + hvv[tt].z * wv.z + hvv[tt].w * wv.w;
                    }
                }
            }
        }
    }

    float m[8];
#pragma unroll
    for (int j = 0; j < 8; ++j) {
        int n = g + 16 * j;
        float cbn = cb[n];
        float mm = -INFINITY;
#pragma unroll
        for (int tt = 0; tt < 4; ++tt) {
            int t = t0 + i + 16 * tt;
            float v = acc[tt][j] + cbn;
            if (t < 8188) mm = fmaxf(mm, v);
        }
        mm = DPP_MAX(mm, 0xB1);
        mm = DPP_MAX(mm, 0x4E);
        mm = DPP_MAX(mm, 0x141);
        mm = DPP_MAX(mm, 0x140);
        m[j] = mm;
    }
    if (i == 0) {
#pragma unroll
        for (int j = 0; j < 8; ++j)
            part[(size_t)blk * 128 + g + 16 * j] = m[j];
    }
}

// ---------------------------------------------------------------------------
// Kernel 4: final head — pool-reduce, logits, log_softmax, loss + acc.
// ---------------------------------------------------------------------------
__global__ void final_head(
    const float* __restrict__ part,
    const float* __restrict__ logits_w,
    const float* __restrict__ logits_b,
    const int* __restrict__ labels,
    float* __restrict__ out)
{
    __shared__ float pooled[128];
    __shared__ float lgt[20];
    int tid = threadIdx.x;
    float mx = -INFINITY;
    for (int b = 0; b < 128; ++b) mx = fmaxf(mx, part[(size_t)b * 128 + tid]);
    pooled[tid] = mx;
    __syncthreads();
    if (tid < 20) {
        float s = logits_b[tid];
        for (int k = 0; k < 128; ++k) s += logits_w[tid * 128 + k] * pooled[k];
        lgt[tid] = s;
    }
    __syncthreads();
    if (tid == 0) {
        float m = lgt[0]; int am = 0;
        for (int c2 = 1; c2 < 20; ++c2) { if (lgt[c2] > m) { m = lgt[c2]; am = c2; } }
        float se = 0.f;
        for (int c2 = 0; c2 < 20; ++c2) se += expf(lgt[c2] - m);
        float lse = m + logf(se);
        int lbl = labels[0];
        out[0] = -(lgt[lbl] - lse);
        out[1] = (am == lbl) ? 1.f : 0.f;
    }
}

// ---------------------------------------------------------------------------
extern "C" void kernel_launch(void* const* d_in, const int* in_sizes, int n_in,
                              void* d_out, int out_size, void* d_ws, size_t ws_size,
                              hipStream_t stream) {
    (void)in_sizes; (void)n_in; (void)out_size;
    const int*   docs   = (const int*)d_in[0];
    const int*   labels = (const int*)d_in[2];
    const float* embW   = (const float*)d_in[4];
    const float* w_ih   = (const float*)d_in[5];
    const float* w_hh   = (const float*)d_in[6];
    const float* b_ih   = (const float*)d_in[7];
    const float* b_hh   = (const float*)d_in[8];
    const float* cw     = (const float*)d_in[9];
    const float* cb     = (const float*)d_in[10];
    const float* lw     = (const float*)d_in[11];
    const float* lb     = (const float*)d_in[12];
    float* out = (float*)d_out;

    char* ws = (char*)d_ws;
    float*    pre  = (float*)(ws);                 // 33554432 B
    float*    hs   = (float*)(ws + 33554432);      //  8388608 B
    float*    part = (float*)(ws + 41943040);      //    65536 B
    unsigned* w6   = (unsigned*)(ws + 42008576);   //   262144 B

    bool ws_ok = (ws_size >= (size_t)42270720);
    hipFuncAttributes aA, a6;
    bool okA = ws_ok
        && (hipFuncGetAttributes(&aA, (const void*)lstm_scan_mx6a) == hipSuccess)
        && (aA.localSizeBytes == 0);
    bool ok6 = ws_ok
        && (hipFuncGetAttributes(&a6, (const void*)lstm_scan_mx6) == hipSuccess)
        && (a6.localSizeBytes == 0);

    gemm_pre<<<dim3(128, 16, 1), 256, 0, stream>>>(docs, embW, w_ih, b_ih, b_hh, pre);
    if (okA || ok6) {
        pack_w6<<<32, 256, 0, stream>>>(w_hh, w6);
        if (okA) lstm_scan_mx6a<<<1, 256, 0, stream>>>(pre, w6, hs);
        else     lstm_scan_mx6<<<1, 512, 0, stream>>>(pre, w6, hs);
    } else {
        lstm_scan_mx8<<<1, 512, 0, stream>>>(pre, w_hh, hs);
    }
    conv_pool<<<128, 256, 0, stream>>>(hs, cw, cb, part);
    final_head<<<1, 128, 0, stream>>>(part, lw, lb, labels, out);
}

// Round 13
// 5125.326 us; speedup vs baseline: 1.2114x; 1.0767x over previous
//
#include <hip/hip_runtime.h>
#include <math.h>

#define T_LEN 8192

typedef float f32x4 __attribute__((ext_vector_type(4)));
typedef int   i32x8 __attribute__((ext_vector_type(8)));
typedef int   i32x6 __attribute__((ext_vector_type(6)));   // fp6 operand tuple

#define DPP_MAX(x, ctrl) fmaxf((x), __int_as_float(__builtin_amdgcn_update_dpp(0, __float_as_int(x), (ctrl), 0xF, 0xF, true)))
#define SB() __builtin_amdgcn_sched_barrier(0)

// LDS-only barrier: drain LDS ops, leave global loads/stores in flight.
#define BAR_LDS() do { \
    __builtin_amdgcn_sched_barrier(0); \
    asm volatile("s_waitcnt lgkmcnt(0)" ::: "memory"); \
    __builtin_amdgcn_s_barrier(); \
    __builtin_amdgcn_sched_barrier(0); \
} while (0)

__device__ __forceinline__ float fexp2(float x) {
#if __has_builtin(__builtin_amdgcn_exp2f)
    return __builtin_amdgcn_exp2f(x);
#else
    return exp2f(x);
#endif
}
__device__ __forceinline__ float rcp1p(float e) {
    return __builtin_amdgcn_rcpf(1.f + e);
}
__device__ __forceinline__ float fsig_c(float x) {
    x = fminf(30.f, fmaxf(-30.f, x));
    float e = __expf(-x);
    return __builtin_amdgcn_rcpf(1.f + e);
}
__device__ __forceinline__ float ftanh_c(float x) {
    x = fminf(15.f, fmaxf(-15.f, x));
    float e = __expf(-2.f * x);
    return (1.f - e) * __builtin_amdgcn_rcpf(1.f + e);
}

// ---- OCP e4m3fn encode ----
__device__ __forceinline__ unsigned char enc_e4m3(float x) {
#if __has_builtin(__builtin_amdgcn_cvt_pk_fp8_f32)
    int v = __builtin_amdgcn_cvt_pk_fp8_f32(x, 0.f, 0, false);
    return (unsigned char)(v & 0xff);
#else
    unsigned u = __float_as_uint(x);
    unsigned s = (u >> 24) & 0x80u;
    float a = fabsf(x);
    if (a > 448.f) a = 448.f;
    if (a < 9.765625e-4f) return (unsigned char)s;
    int e = ((int)((__float_as_uint(a) >> 23) & 0xffu)) - 127;
    int eu = e < -6 ? -6 : e;
    float ulp = exp2f((float)(eu - 3));
    float q = rintf(a / ulp);
    int mant, ee;
    if (eu == -6 && q < 8.f) { mant = (int)q; ee = 0; }
    else {
        if (q >= 16.f) { q *= 0.5f; eu += 1; }
        mant = (int)q - 8; ee = eu + 7;
        if (ee > 15 || (ee == 15 && mant > 6)) { ee = 15; mant = 6; }
    }
    return (unsigned char)(s | (unsigned)(ee << 3) | (unsigned)mant);
#endif
}
__device__ __forceinline__ unsigned pk4(float a, float b, float c, float d) {
    return (unsigned)enc_e4m3(a) | ((unsigned)enc_e4m3(b) << 8)
         | ((unsigned)enc_e4m3(c) << 16) | ((unsigned)enc_e4m3(d) << 24);
}

// ---- OCP e2m3 (fp6) encode: full version (pre-pass only) ----
__device__ __forceinline__ unsigned enc_e2m3(float x) {
    unsigned s = (__float_as_uint(x) >> 31) << 5;
    float a = fabsf(x);
    a = fminf(a, 7.5f);
    if (a < 0.0625f) return s;
    int e = ((int)((__float_as_uint(a) >> 23) & 0xffu)) - 127;
    int eu = e < 0 ? 0 : e;
    float ulp = __int_as_float((unsigned)(eu + 124) << 23);     // 2^(eu-3)
    float q = rintf(a * __builtin_amdgcn_rcpf(ulp));
    int E, M;
    if (e < 0) {
        if (q >= 8.f) { E = 1; M = 0; }
        else { E = 0; M = (int)q; }
    } else {
        if (q >= 16.f) { q = 8.f; eu += 1; }
        if (eu > 2) { E = 3; M = 7; }
        else { E = eu + 1; M = (int)q - 8; }
    }
    return s | (unsigned)(E << 3) | (unsigned)M;
}

// ---- fast e2m3 for |h|<1 (a=4|h|<4): piecewise-linear, bit-identical ----
__device__ __forceinline__ int enc_e2m3_h4(float h) {
    float x = h * 4.f;
    float a = fabsf(x);
    int c1 = (int)rintf(a * 8.f);
    int c2 = (int)rintf(a * 4.f) + 8;
    int mag = (a < 2.f) ? c1 : c2;
    return mag | (int)((__float_as_uint(h) >> 26) & 32u);
}

// ---------------------------------------------------------------------------
// Kernel 0b: pre-pass pack for the DPP-quad layout (primary scan).
// Tile gt=16w+rt, tile-row rw=4kg+g  <->  W_hh row g*256 + 64w + rt + 16kg.
// ---------------------------------------------------------------------------
__global__ __launch_bounds__(256) void pack_w6b(
    const float* __restrict__ w_hh,   // (1024, 256)
    unsigned* __restrict__ w6)        // 8192 items x 8 dwords (6 used)
{
    int idx = blockIdx.x * 256 + threadIdx.x;   // 0..8191
    int l  = idx & 63;
    int kt = (idx >> 6) & 1;
    int gt = idx >> 7;                            // 0..63
    int rw = l & 15, ks = l >> 4;
    int orow = ((rw & 3) << 8) + 64 * (gt >> 4) + (gt & 15) + 16 * (rw >> 2);
    const float* s = w_hh + (size_t)orow * 256 + 128 * kt + 32 * ks;
    unsigned d[6] = {0, 0, 0, 0, 0, 0};
#pragma unroll
    for (int j = 0; j < 32; ++j) {
        unsigned c = enc_e2m3(s[j] * 32.f);
        int bit = 6 * j;
        d[bit >> 5] |= c << (bit & 31);
        if ((bit & 31) > 26) d[(bit >> 5) + 1] |= c >> (32 - (bit & 31));
    }
    unsigned* o = w6 + (size_t)idx * 8;
    o[0] = d[0]; o[1] = d[1]; o[2] = d[2];
    o[3] = d[3]; o[4] = d[4]; o[5] = d[5];
    o[6] = 0;    o[7] = 0;
}

// ---------------------------------------------------------------------------
// Kernel 0a: pre-pass pack, r12 mapping (fallback scan mx6a).
// ---------------------------------------------------------------------------
__global__ __launch_bounds__(256) void pack_w6a(
    const float* __restrict__ w_hh,
    unsigned* __restrict__ w6)
{
    int idx = blockIdx.x * 256 + threadIdx.x;
    int l  = idx & 63;
    int kt = (idx >> 6) & 1;
    int gt = idx >> 7;
    int rw = l & 15, ks = l >> 4;
    int rowp = (gt << 4) + rw;
    int orow = ((rowp & 3) << 8) + (rowp >> 2);
    const float* s = w_hh + (size_t)orow * 256 + 128 * kt + 32 * ks;
    unsigned d[6] = {0, 0, 0, 0, 0, 0};
#pragma unroll
    for (int j = 0; j < 32; ++j) {
        unsigned c = enc_e2m3(s[j] * 32.f);
        int bit = 6 * j;
        d[bit >> 5] |= c << (bit & 31);
        if ((bit & 31) > 26) d[(bit >> 5) + 1] |= c >> (32 - (bit & 31));
    }
    unsigned* o = w6 + (size_t)idx * 8;
    o[0] = d[0]; o[1] = d[1]; o[2] = d[2];
    o[3] = d[3]; o[4] = d[4]; o[5] = d[5];
    o[6] = 0;    o[7] = 0;
}

// ---------------------------------------------------------------------------
// Kernel 1: pre = relu(embed_W[docs]) @ w_ih^T + (b_ih + b_hh)   (T x 1024)
// Output columns PERMUTED: col' = 4*unit + gate
// ---------------------------------------------------------------------------
__global__ __launch_bounds__(256, 4) void gemm_pre(
    const int* __restrict__ docs,
    const float* __restrict__ embW,
    const float* __restrict__ w_ih,
    const float* __restrict__ b_ih,
    const float* __restrict__ b_hh,
    float* __restrict__ pre)
{
    __shared__ __align__(16) float As[16][68];
    __shared__ __align__(16) float Bs[16][68];
    __shared__ int rowid[64];
    const int bt = blockIdx.x;
    const int bj = blockIdx.y;
    const int tid = threadIdx.x;
    if (tid < 64) rowid[tid] = docs[bt * 64 + tid];
    __syncthreads();
    const int ti = tid & 15, tj = tid >> 4;
    const int r = tid & 63;
    const int kk4 = (tid >> 6) * 4;
    float acc[4][4];
#pragma unroll
    for (int ii = 0; ii < 4; ++ii)
#pragma unroll
        for (int jj = 0; jj < 4; ++jj) acc[ii][jj] = 0.f;

    for (int k0 = 0; k0 < 256; k0 += 16) {
        float4 av = *(const float4*)(embW + (size_t)rowid[r] * 256 + k0 + kk4);
        float4 bv = *(const float4*)(w_ih + (size_t)(bj * 64 + r) * 256 + k0 + kk4);
        As[kk4 + 0][r] = fmaxf(av.x, 0.f);
        As[kk4 + 1][r] = fmaxf(av.y, 0.f);
        As[kk4 + 2][r] = fmaxf(av.z, 0.f);
        As[kk4 + 3][r] = fmaxf(av.w, 0.f);
        Bs[kk4 + 0][r] = bv.x;
        Bs[kk4 + 1][r] = bv.y;
        Bs[kk4 + 2][r] = bv.z;
        Bs[kk4 + 3][r] = bv.w;
        __syncthreads();
#pragma unroll
        for (int kk = 0; kk < 16; ++kk) {
            float4 a = *(const float4*)&As[kk][ti * 4];
            float4 b = *(const float4*)&Bs[kk][tj * 4];
            acc[0][0] += a.x * b.x; acc[0][1] += a.x * b.y; acc[0][2] += a.x * b.z; acc[0][3] += a.x * b.w;
            acc[1][0] += a.y * b.x; acc[1][1] += a.y * b.y; acc[1][2] += a.y * b.z; acc[1][3] += a.y * b.w;
            acc[2][0] += a.z * b.x; acc[2][1] += a.z * b.y; acc[2][2] += a.z * b.z; acc[2][3] += a.z * b.w;
            acc[3][0] += a.w * b.x; acc[3][1] += a.w * b.y; acc[3][2] += a.w * b.z; acc[3][3] += a.w * b.w;
        }
        __syncthreads();
    }
#pragma unroll
    for (int ii = 0; ii < 4; ++ii) {
        int t = bt * 64 + ti * 4 + ii;
#pragma unroll
        for (int jj = 0; jj < 4; ++jj) {
            int j = bj * 64 + tj * 4 + jj;
            int jp = ((j & 255) << 2) | (j >> 8);
            pre[(size_t)t * 1024 + jp] = acc[ii][jj] + b_ih[j] + b_hh[j];
        }
    }
}

// fp6 MFMA pair: kt=0 (C = pinned zero) chained into kt=1; A from AGPRs.
#define MFMA_PAIR(RT, DST) \
    asm("v_mfma_scale_f32_16x16x128_f8f6f4 %0, %1, %2, %5, %6, %6 cbsz:2 blgp:2\n\t" \
        "v_mfma_scale_f32_16x16x128_f8f6f4 %0, %3, %4, %0, %6, %6 cbsz:2 blgp:2" \
        : "=&v"(DST) \
        : "a"(wA[RT][0]), "v"(bq0), "a"(wA[RT][1]), "v"(bq1), "v"(CZ), "v"(sc))

// ---------------------------------------------------------------------------
// Kernel 2a (primary): 4-wave MX-fp6 scan, DPP-quad pack, interleaved selects.
// Lane l owns unit u = 64w + (l&15) + 16*(l>>4); each DPP quad owns an
// aligned quad of units -> 6-bit pack = 1 quad_perm + 2 ALU + 1 byte write
// (no ds_bpermute). Leaf selects pinned 2+ MFMA-pairs behind producers via
// sched_barrier(0) groups -> VALU hides under the MFMA phase if HW overlaps.
// ---------------------------------------------------------------------------
__global__ __launch_bounds__(256, 1) void lstm_scan_mx6b(
    const float* __restrict__ pre,    // (T, 1024), permuted cols 4u+gate
    const unsigned* __restrict__ w6,  // packed fp6 weights (pack_w6b layout)
    float* __restrict__ hs)           // (T, 256) fp32
{
    const int tid = threadIdx.x;
    const int w  = tid >> 6;          // wave 0..3
    const int l  = tid & 63;
    const int rto = l & 15;           // owned tile = column
    const int kgr = l >> 4;           // B k-slice / row-block
    const float C_L2E  = -1.4426950408889634f;
    const float C_L2E2 = -2.8853900817779268f;
    const float I_L2E  = C_L2E  / 128.f;
    const float I_L2E2 = C_L2E2 / 128.f;

    __shared__ __align__(32) unsigned char h6pk[2][256];  // 8 windows x 32B

    // ---- weights: 16 tiles x 2 kt as 6-dword fp6 tuples (AGPR-resident) ----
    i32x6 wA[16][2];
#pragma unroll
    for (int rtt = 0; rtt < 16; ++rtt) {
#pragma unroll
        for (int kt = 0; kt < 2; ++kt) {
            int gt = 16 * w + rtt;
            const unsigned* s = w6 + (size_t)((gt * 2 + kt) * 64 + l) * 8;
            uint4 lo = *(const uint4*)s;
            uint2 hi = *(const uint2*)(s + 4);
            i32x6 v;
            v[0] = (int)lo.x; v[1] = (int)lo.y; v[2] = (int)lo.z;
            v[3] = (int)lo.w; v[4] = (int)hi.x; v[5] = (int)hi.y;
            wA[rtt][kt] = v;
        }
    }

    for (int i = tid; i < 512; i += 256) ((unsigned char*)h6pk)[i] = 0;

    const int u = 64 * w + rto + 16 * kgr;                // owned unit
    float c_st = 0.f;

    const bool b0 = (rto & 1), b1 = (rto & 2), b2 = (rto & 4), b3 = (rto & 8);

    // DPP-quad pack constants: quad q = l>>2, G = 4*(q>>2) + (q&3)
    const int qi  = l & 3;
    const bool iswr = (qi < 3);
    const int rsh = 2 * qi;
    const int qq  = l >> 2;
    const int G   = 4 * (qq >> 2) + (qq & 3);
    const int wofs = (2 * w + (G >> 3)) * 32 + 3 * (G & 7) + qi;

    f32x4 CZ = (f32x4){0.f, 0.f, 0.f, 0.f};
    asm("" : "+v"(CZ));                                   // pin zero tuple
    int sc = 0x7f7f7f7f;                                  // e8m0 scale = 1.0

    f32x4 p4c = *(const f32x4*)(pre + 4 * u);             // t = 0
    float tx = p4c.x * C_L2E;
    float ty = p4c.y * C_L2E;
    float tz = p4c.z * C_L2E2;
    float tw = p4c.w * C_L2E;
    const float* pp = pre + 1024 + 4 * u;
    float* hsp = hs + u;
    const unsigned char* h6base = (const unsigned char*)h6pk;
    BAR_LDS();

#define LSTM_STEP(RD, WR) do { \
    f32x4 p4n = *(const f32x4*)pp; pp += 1024; \
    i32x6 bq0, bq1; \
    { \
        const unsigned char* bp0 = h6base + (RD) + kgr * 32; \
        uint4 lo = *(const uint4*)bp0; \
        uint2 hi = *(const uint2*)(bp0 + 16); \
        bq0[0] = (int)lo.x; bq0[1] = (int)lo.y; bq0[2] = (int)lo.z; \
        bq0[3] = (int)lo.w; bq0[4] = (int)hi.x; bq0[5] = (int)hi.y; \
        const unsigned char* bp1 = bp0 + 128; \
        uint4 lo1 = *(const uint4*)bp1; \
        uint2 hi1 = *(const uint2*)(bp1 + 16); \
        bq1[0] = (int)lo1.x; bq1[1] = (int)lo1.y; bq1[2] = (int)lo1.z; \
        bq1[3] = (int)lo1.w; bq1[4] = (int)hi1.x; bq1[5] = (int)hi1.y; \
    } \
    f32x4 a0, a1, a2, a3, a4, a5, a6, a7, a8, a9, a10, a11, a12, a13, a14, a15; \
    MFMA_PAIR(0, a0);  MFMA_PAIR(1, a1);  MFMA_PAIR(2, a2);  MFMA_PAIR(3, a3); \
    SB(); \
    f32x4 s0 = b0 ? a1 : a0; \
    MFMA_PAIR(4, a4);  MFMA_PAIR(5, a5);  SB(); \
    f32x4 s1 = b0 ? a3 : a2; \
    MFMA_PAIR(6, a6);  MFMA_PAIR(7, a7);  SB(); \
    f32x4 s2 = b0 ? a5 : a4; \
    MFMA_PAIR(8, a8);  MFMA_PAIR(9, a9);  SB(); \
    f32x4 s3 = b0 ? a7 : a6; \
    f32x4 q0 = b1 ? s1 : s0; \
    MFMA_PAIR(10, a10); MFMA_PAIR(11, a11); SB(); \
    f32x4 s4 = b0 ? a9 : a8; \
    MFMA_PAIR(12, a12); MFMA_PAIR(13, a13); SB(); \
    f32x4 s5 = b0 ? a11 : a10; \
    f32x4 q1 = b1 ? s3 : s2; \
    MFMA_PAIR(14, a14); MFMA_PAIR(15, a15); SB(); \
    f32x4 s6 = b0 ? a13 : a12; \
    asm volatile("s_nop 7\n\ts_nop 7" : "+v"(a14), "+v"(a15)); \
    f32x4 s7 = b0 ? a15 : a14; \
    f32x4 q2 = b1 ? s5 : s4; \
    f32x4 q3 = b1 ? s7 : s6; \
    f32x4 r0 = b2 ? q1 : q0; \
    f32x4 r1 = b2 ? q3 : q2; \
    f32x4 av = b3 ? r1 : r0; \
    float nx = p4n.x * C_L2E, ny = p4n.y * C_L2E; \
    float nz = p4n.z * C_L2E2, nw = p4n.w * C_L2E; \
    float si = rcp1p(fexp2(fmaf(av.x, I_L2E,  tx))); \
    float sf = rcp1p(fexp2(fmaf(av.y, I_L2E,  ty))); \
    float tg = 2.f * rcp1p(fexp2(fmaf(av.z, I_L2E2, tz))) - 1.f; \
    float so = rcp1p(fexp2(fmaf(av.w, I_L2E,  tw))); \
    c_st = sf * c_st + si * tg; \
    float h = so * (2.f * rcp1p(fexp2(c_st * C_L2E2)) - 1.f); \
    hsp[0] = h; hsp += 256; \
    int code = enc_e2m3_h4(h); \
    int cnx = __builtin_amdgcn_update_dpp(0, code, 0x39, 0xF, 0xF, true); \
    if (iswr) { \
        unsigned byte = (((unsigned)code >> rsh) | ((unsigned)cnx << (6 - rsh))) & 0xffu; \
        *((unsigned char*)h6pk + (WR) + wofs) = (unsigned char)byte; \
    } \
    tx = nx; ty = ny; tz = nz; tw = nw; \
    BAR_LDS(); \
} while (0)

    for (int t2 = 0; t2 < T_LEN; t2 += 2) {
        LSTM_STEP(256, 0);    // even step: read parity 1, write parity 0
        LSTM_STEP(0, 256);    // odd step: read parity 0, write parity 1
    }
#undef LSTM_STEP
}

// ---------------------------------------------------------------------------
// Kernel 2b (fallback 1): r12 proven 4-wave fp6 scan (pack_w6a layout).
// ---------------------------------------------------------------------------
__global__ __launch_bounds__(256, 1) void lstm_scan_mx6a(
    const float* __restrict__ pre,
    const unsigned* __restrict__ w6,
    float* __restrict__ hs)
{
    const int tid = threadIdx.x;
    const int w  = tid >> 6;
    const int l  = tid & 63;
    const int rto = l & 15;
    const int kg  = l >> 4;
    const float C_L2E  = -1.4426950408889634f;
    const float C_L2E2 = -2.8853900817779268f;
    const float I_L2E  = C_L2E  / 128.f;
    const float I_L2E2 = C_L2E2 / 128.f;

    __shared__ __align__(32) unsigned char h6pk[2][256];

    i32x6 wA[16][2];
#pragma unroll
    for (int rtt = 0; rtt < 16; ++rtt) {
#pragma unroll
        for (int kt = 0; kt < 2; ++kt) {
            int gt = 16 * w + rtt;
            const unsigned* s = w6 + (size_t)((gt * 2 + kt) * 64 + l) * 8;
            uint4 lo = *(const uint4*)s;
            uint2 hi = *(const uint2*)(s + 4);
            i32x6 v;
            v[0] = (int)lo.x; v[1] = (int)lo.y; v[2] = (int)lo.z;
            v[3] = (int)lo.w; v[4] = (int)hi.x; v[5] = (int)hi.y;
            wA[rtt][kt] = v;
        }
    }

    for (int i = tid; i < 512; i += 256) ((unsigned char*)h6pk)[i] = 0;

    const int u = 64 * w + 4 * rto + kg;
    float c_st = 0.f;

    const bool b0 = (rto & 1), b1 = (rto & 2), b2 = (rto & 4), b3 = (rto & 8);

    const bool iswr = (l < 48);
    const int s_  = (l >= 24) ? 1 : 0;
    const int b_  = l - 24 * s_;
    const int j0  = (4 * b_) / 3;
    const int rsh = 8 * b_ - 6 * j0;
    const int j1  = j0 + 1;
    const int lj0 = 16 * (j0 & 3) + 8 * s_ + (j0 >> 2);
    const int lj1 = 16 * (j1 & 3) + 8 * s_ + (j1 >> 2);
    const int wofs = (2 * w + s_) * 32 + b_;

    f32x4 CZ = (f32x4){0.f, 0.f, 0.f, 0.f};
    asm("" : "+v"(CZ));
    int sc = 0x7f7f7f7f;

    f32x4 p4c = *(const f32x4*)(pre + 4 * u);
    float tx = p4c.x * C_L2E;
    float ty = p4c.y * C_L2E;
    float tz = p4c.z * C_L2E2;
    float tw = p4c.w * C_L2E;
    const float* pp = pre + 1024 + 4 * u;
    float* hsp = hs + u;
    const unsigned char* h6base = (const unsigned char*)h6pk;
    BAR_LDS();

#define LSTM_STEP(RD, WR) do { \
    f32x4 p4n = *(const f32x4*)pp; pp += 1024; \
    i32x6 bq0, bq1; \
    { \
        const unsigned char* bp0 = h6base + (RD) + kg * 32; \
        uint4 lo = *(const uint4*)bp0; \
        uint2 hi = *(const uint2*)(bp0 + 16); \
        bq0[0] = (int)lo.x; bq0[1] = (int)lo.y; bq0[2] = (int)lo.z; \
        bq0[3] = (int)lo.w; bq0[4] = (int)hi.x; bq0[5] = (int)hi.y; \
        const unsigned char* bp1 = bp0 + 128; \
        uint4 lo1 = *(const uint4*)bp1; \
        uint2 hi1 = *(const uint2*)(bp1 + 16); \
        bq1[0] = (int)lo1.x; bq1[1] = (int)lo1.y; bq1[2] = (int)lo1.z; \
        bq1[3] = (int)lo1.w; bq1[4] = (int)hi1.x; bq1[5] = (int)hi1.y; \
    } \
    f32x4 a0, a1, a2, a3, a4, a5, a6, a7, a8, a9, a10, a11, a12, a13, a14, a15; \
    MFMA_PAIR(0, a0);  MFMA_PAIR(1, a1);  MFMA_PAIR(2, a2);  MFMA_PAIR(3, a3); \
    MFMA_PAIR(4, a4);  MFMA_PAIR(5, a5);  MFMA_PAIR(6, a6);  MFMA_PAIR(7, a7); \
    MFMA_PAIR(8, a8);  MFMA_PAIR(9, a9);  MFMA_PAIR(10, a10); MFMA_PAIR(11, a11); \
    MFMA_PAIR(12, a12); MFMA_PAIR(13, a13); MFMA_PAIR(14, a14); MFMA_PAIR(15, a15); \
    asm volatile("s_nop 7\n\ts_nop 7\n\ts_nop 7" \
        : "+v"(a0), "+v"(a1), "+v"(a2), "+v"(a3), "+v"(a4), "+v"(a5), "+v"(a6), "+v"(a7), \
          "+v"(a8), "+v"(a9), "+v"(a10), "+v"(a11), "+v"(a12), "+v"(a13), "+v"(a14), "+v"(a15)); \
    f32x4 s0 = b0 ? a1  : a0; \
    f32x4 s1 = b0 ? a3  : a2; \
    f32x4 s2 = b0 ? a5  : a4; \
    f32x4 s3 = b0 ? a7  : a6; \
    f32x4 s4 = b0 ? a9  : a8; \
    f32x4 s5 = b0 ? a11 : a10; \
    f32x4 s6 = b0 ? a13 : a12; \
    f32x4 s7 = b0 ? a15 : a14; \
    f32x4 q0 = b1 ? s1 : s0; \
    f32x4 q1 = b1 ? s3 : s2; \
    f32x4 q2 = b1 ? s5 : s4; \
    f32x4 q3 = b1 ? s7 : s6; \
    f32x4 r0 = b2 ? q1 : q0; \
    f32x4 r1 = b2 ? q3 : q2; \
    f32x4 av = b3 ? r1 : r0; \
    float nx = p4n.x * C_L2E, ny = p4n.y * C_L2E; \
    float nz = p4n.z * C_L2E2, nw = p4n.w * C_L2E; \
    float si = rcp1p(fexp2(fmaf(av.x, I_L2E,  tx))); \
    float sf = rcp1p(fexp2(fmaf(av.y, I_L2E,  ty))); \
    float tg = 2.f * rcp1p(fexp2(fmaf(av.z, I_L2E2, tz))) - 1.f; \
    float so = rcp1p(fexp2(fmaf(av.w, I_L2E,  tw))); \
    c_st = sf * c_st + si * tg; \
    float h = so * (2.f * rcp1p(fexp2(c_st * C_L2E2)) - 1.f); \
    hsp[0] = h; hsp += 256; \
    int code = enc_e2m3_h4(h); \
    int c0 = __shfl(code, lj0, 64); \
    int c1 = __shfl(code, lj1, 64); \
    if (iswr) { \
        unsigned byte = (((unsigned)c0 >> rsh) | ((unsigned)c1 << (6 - rsh))) & 0xffu; \
        *((unsigned char*)h6pk + (WR) + wofs) = (unsigned char)byte; \
    } \
    tx = nx; ty = ny; tz = nz; tw = nw; \
    BAR_LDS(); \
} while (0)

    for (int t2 = 0; t2 < T_LEN; t2 += 2) {
        LSTM_STEP(256, 0);
        LSTM_STEP(0, 256);
    }
#undef LSTM_STEP
}

// ---------------------------------------------------------------------------
// Kernel 2c (fallback 2): round-6 proven MX-fp8 scan.
// ---------------------------------------------------------------------------
__global__ __launch_bounds__(512, 2) void lstm_scan_mx8(
    const float* __restrict__ pre,
    const float* __restrict__ w_hh,
    float* __restrict__ hs)
{
    const int tid = threadIdx.x;
    const int w  = tid >> 6;
    const int l  = tid & 63;
    const int rw = l & 15;
    const int kg = l >> 4;
    const float INV = 1.f / 32768.f;

    __shared__ __align__(16) unsigned char h8[2 * 256];
    __shared__ __align__(16) float ldsPre[2][1024];

    i32x8 wA[8][2];
#pragma unroll
    for (int rt = 0; rt < 8; ++rt) {
#pragma unroll
        for (int kt = 0; kt < 2; ++kt) {
            int rowp = ((8 * w + rt) << 4) + rw;
            int orow = ((rowp & 3) << 8) + (rowp >> 2);
            const float* s = w_hh + (size_t)orow * 256 + 128 * kt + 32 * kg;
            i32x8 v;
#pragma unroll
            for (int d = 0; d < 8; ++d) {
                float4 f = *(const float4*)(s + 4 * d);
                v[d] = (int)pk4(f.x * 512.f, f.y * 512.f, f.z * 512.f, f.w * 512.f);
            }
            wA[rt][kt] = v;
        }
    }

    for (int i = tid; i < 512; i += 512) h8[i] = 0;
    {
        float2 p = *(const float2*)(pre + 2 * tid);
        *(float2*)&ldsPre[0][2 * tid] = p;
    }
    float c_st = 0.f;
    const bool isup = (rw < 8);
    const int u = 32 * w + 4 * (rw & 7) + kg;
    const float* pnext = pre + 1024 + 2 * tid;
    float* hsp = hs + u;
    __syncthreads();

    for (int t = 0; t < T_LEN; ++t) {
        const int PW = t & 1;
        const int PR = PW ^ 1;

        f32x4 p4 = *(const f32x4*)&ldsPre[PW][4 * u];

        float2 pv = *(const float2*)pnext;
        if (t + 2 < T_LEN) pnext += 1024;

        i32x8 bq[2];
#pragma unroll
        for (int kt = 0; kt < 2; ++kt) {
            const unsigned char* bp = &h8[PR * 256 + 128 * kt + 32 * kg];
            uint4 lo = *(const uint4*)bp;
            uint4 hi = *(const uint4*)(bp + 16);
            i32x8 b;
            b[0] = (int)lo.x; b[1] = (int)lo.y; b[2] = (int)lo.z; b[3] = (int)lo.w;
            b[4] = (int)hi.x; b[5] = (int)hi.y; b[6] = (int)hi.z; b[7] = (int)hi.w;
            bq[kt] = b;
        }

        f32x4 acc[8];
#pragma unroll
        for (int rt = 0; rt < 8; ++rt) acc[rt] = (f32x4){0.f, 0.f, 0.f, 0.f};
#pragma unroll
        for (int rt = 0; rt < 8; ++rt)
#pragma unroll
            for (int kt = 0; kt < 2; ++kt)
                acc[rt] = __builtin_amdgcn_mfma_scale_f32_16x16x128_f8f6f4(
                    wA[rt][kt], bq[kt], acc[rt],
                    0, 0, 0, 0x7f7f7f7f, 0, 0x7f7f7f7f);

        if (isup) {
            f32x4 av = acc[0];
            av = (rw == 1) ? acc[1] : av;
            av = (rw == 2) ? acc[2] : av;
            av = (rw == 3) ? acc[3] : av;
            av = (rw == 4) ? acc[4] : av;
            av = (rw == 5) ? acc[5] : av;
            av = (rw == 6) ? acc[6] : av;
            av = (rw == 7) ? acc[7] : av;
            float gi = fmaf(av.x, INV, p4.x);
            float gf = fmaf(av.y, INV, p4.y);
            float gg = fmaf(av.z, INV, p4.z);
            float go = fmaf(av.w, INV, p4.w);
            float si = fsig_c(gi);
            float sf = fsig_c(gf);
            float tg = ftanh_c(gg);
            float so = fsig_c(go);
            c_st = sf * c_st + si * tg;
            float h = so * ftanh_c(c_st);
            hsp[0] = h;
            h8[PW * 256 + u] = enc_e4m3(h * 64.f);
        }
        hsp += 256;

        *(float2*)&ldsPre[PR][2 * tid] = pv;

        __syncthreads();
    }
}

// ---------------------------------------------------------------------------
// Kernel 3: conv (FN=128, FL=5) over hs + per-block max over its 64 t's.
// ---------------------------------------------------------------------------
__global__ __launch_bounds__(256) void conv_pool(
    const float* __restrict__ hs,
    const float* __restrict__ cw,
    const float* __restrict__ cb,
    float* __restrict__ part)
{
    __shared__ __align__(16) float hst[68 * 260];
    __shared__ __align__(16) float cwS[128 * 68];
    const int blk = blockIdx.x;
    const int t0 = blk * 64;
    const int tid = threadIdx.x;
    const int i = tid & 15;
    const int g = tid >> 4;

    for (int e = tid; e < 68 * 64; e += 256) {
        int rr = e >> 6;
        int c4 = (e & 63) * 4;
        int tg = t0 + rr; if (tg > 8191) tg = 8191;
        float4 v = *(const float4*)(hs + (size_t)tg * 256 + c4);
        *(float4*)&hst[rr * 260 + c4] = v;
    }

    float acc[4][8];
#pragma unroll
    for (int tt = 0; tt < 4; ++tt)
#pragma unroll
        for (int j = 0; j < 8; ++j) acc[tt][j] = 0.f;

    for (int l = 0; l < 5; ++l) {
        for (int hc = 0; hc < 4; ++hc) {
            __syncthreads();
            {
                int n = tid >> 1;
                int hb = (tid & 1) * 32;
                const float* src = cw + (size_t)n * 1280 + l * 256 + hc * 64 + hb;
                float* dst = &cwS[n * 68 + hb];
#pragma unroll
                for (int q = 0; q < 8; ++q) {
                    float4 v = *(const float4*)(src + 4 * q);
                    *(float4*)(dst + 4 * q) = v;
                }
            }
            __syncthreads();
#pragma unroll 4
            for (int q = 0; q < 16; ++q) {
                float4 hvv[4];
#pragma unroll
                for (int tt = 0; tt < 4; ++tt)
                    hvv[tt] = *(const float4*)&hst[(i + 16 * tt + l) * 260 + hc * 64 + 4 * q];
#pragma unroll
                for (int j = 0; j < 8; ++j) {
                    float4 wv = *(const float4*)&cwS[(g + 16 * j) * 68 + 4 * q];
#pragma unroll
                    for (int tt = 0; tt < 4; ++tt) {
                        acc[tt][j] += hvv[tt].x * wv.x + hvv[tt].y * wv.y
                                    + hvv[tt].z * wv.z + hvv[tt].w * wv.w;
                    }
                }
            }
        }
    }

    float m[8];
#pragma unroll
    for (int j = 0; j < 8; ++j) {
        int n = g + 16 * j;
        float cbn = cb[n];
        float mm = -INFINITY;
#pragma unroll
        for (int tt = 0; tt < 4; ++tt) {
            int t = t0 + i + 16 * tt;
            float v = acc[tt][j] + cbn;
            if (t < 8188) mm = fmaxf(mm, v);
        }
        mm = DPP_MAX(mm, 0xB1);
        mm = DPP_MAX(mm, 0x4E);
        mm = DPP_MAX(mm, 0x141);
        mm = DPP_MAX(mm, 0x140);
        m[j] = mm;
    }
    if (i == 0) {
#pragma unroll
        for (int j = 0; j < 8; ++j)
            part[(size_t)blk * 128 + g + 16 * j] = m[j];
    }
}

// ---------------------------------------------------------------------------
// Kernel 4: final head — pool-reduce, logits, log_softmax, loss + acc.
// ---------------------------------------------------------------------------
__global__ void final_head(
    const float* __restrict__ part,
    const float* __restrict__ logits_w,
    const float* __restrict__ logits_b,
    const int* __restrict__ labels,
    float* __restrict__ out)
{
    __shared__ float pooled[128];
    __shared__ float lgt[20];
    int tid = threadIdx.x;
    float mx = -INFINITY;
    for (int b = 0; b < 128; ++b) mx = fmaxf(mx, part[(size_t)b * 128 + tid]);
    pooled[tid] = mx;
    __syncthreads();
    if (tid < 20) {
        float s = logits_b[tid];
        for (int k = 0; k < 128; ++k) s += logits_w[tid * 128 + k] * pooled[k];
        lgt[tid] = s;
    }
    __syncthreads();
    if (tid == 0) {
        float m = lgt[0]; int am = 0;
        for (int c2 = 1; c2 < 20; ++c2) { if (lgt[c2] > m) { m = lgt[c2]; am = c2; } }
        float se = 0.f;
        for (int c2 = 0; c2 < 20; ++c2) se += expf(lgt[c2] - m);
        float lse = m + logf(se);
        int lbl = labels[0];
        out[0] = -(lgt[lbl] - lse);
        out[1] = (am == lbl) ? 1.f : 0.f;
    }
}

// ---------------------------------------------------------------------------
extern "C" void kernel_launch(void* const* d_in, const int* in_sizes, int n_in,
                              void* d_out, int out_size, void* d_ws, size_t ws_size,
                              hipStream_t stream) {
    (void)in_sizes; (void)n_in; (void)out_size;
    const int*   docs   = (const int*)d_in[0];
    const int*   labels = (const int*)d_in[2];
    const float* embW   = (const float*)d_in[4];
    const float* w_ih   = (const float*)d_in[5];
    const float* w_hh   = (const float*)d_in[6];
    const float* b_ih   = (const float*)d_in[7];
    const float* b_hh   = (const float*)d_in[8];
    const float* cw     = (const float*)d_in[9];
    const float* cb     = (const float*)d_in[10];
    const float* lw     = (const float*)d_in[11];
    const float* lb     = (const float*)d_in[12];
    float* out = (float*)d_out;

    char* ws = (char*)d_ws;
    float*    pre  = (float*)(ws);                 // 33554432 B
    float*    hs   = (float*)(ws + 33554432);      //  8388608 B
    float*    part = (float*)(ws + 41943040);      //    65536 B
    unsigned* w6   = (unsigned*)(ws + 42008576);   //   262144 B

    bool ws_ok = (ws_size >= (size_t)42270720);
    hipFuncAttributes aB, aA;
    bool okB = ws_ok
        && (hipFuncGetAttributes(&aB, (const void*)lstm_scan_mx6b) == hipSuccess)
        && (aB.localSizeBytes == 0);
    bool okA = ws_ok
        && (hipFuncGetAttributes(&aA, (const void*)lstm_scan_mx6a) == hipSuccess)
        && (aA.localSizeBytes == 0);

    gemm_pre<<<dim3(128, 16, 1), 256, 0, stream>>>(docs, embW, w_ih, b_ih, b_hh, pre);
    if (okB) {
        pack_w6b<<<32, 256, 0, stream>>>(w_hh, w6);
        lstm_scan_mx6b<<<1, 256, 0, stream>>>(pre, w6, hs);
    } else if (okA) {
        pack_w6a<<<32, 256, 0, stream>>>(w_hh, w6);
        lstm_scan_mx6a<<<1, 256, 0, stream>>>(pre, w6, hs);
    } else {
        lstm_scan_mx8<<<1, 512, 0, stream>>>(pre, w_hh, hs);
    }
    conv_pool<<<128, 256, 0, stream>>>(hs, cw, cb, part);
    final_head<<<1, 128, 0, stream>>>(part, lw, lb, labels, out);
}